// Round 16
// baseline (1096.057 us; speedup 1.0000x reference)
//
#include <hip/hip_runtime.h>
#include <hip/hip_bf16.h>
#include <math.h>

#define PI_F 3.14159265358979323846f
// ci16 permutation (involution, swaps bits 2<->3): storage slot s holds channel PERM4(s)
#define PERM4(s) ((((s)&3)) + 8*(((s)>>2)&1) + 4*((s)>>3))

typedef short bfrag __attribute__((ext_vector_type(8)));   // 8 bf16 (4 VGPR)
typedef float f32x4 __attribute__((ext_vector_type(4)));
typedef float f32x16 __attribute__((ext_vector_type(16)));
typedef unsigned short us8 __attribute__((ext_vector_type(8)));

__device__ inline unsigned bf16rne(float x) {
    unsigned u = __builtin_bit_cast(unsigned, x);
    return (u + 0x7fffu + ((u >> 16) & 1u)) >> 16;
}
__device__ inline unsigned packbf2(float a, float b) {
    return bf16rne(a) | (bf16rne(b) << 16);
}
__device__ inline float bf2f(unsigned short u) {
    return __builtin_bit_cast(float, (unsigned)u << 16);
}
__device__ inline void glds16(const unsigned short* g, unsigned char* l) {
    __builtin_amdgcn_global_load_lds(
        (const __attribute__((address_space(1))) unsigned int*)g,
        (__attribute__((address_space(3))) unsigned int*)l, 16, 0, 0);
}

// ---------------------------------------------------------------------------
// conv_v10: MFMA implicit-GEMM 3x3 conv, pad 1, 32x32x16 bf16, W=256 ONLY.
// Double-buffered LDS (glds staging) + REGISTER double-buffered A-frags:
// each cs-group's 9xCT weight fragments are prefetched one phase ahead and
// issued BEFORE the STAGE glds, so no MFMA phase waits on vmem (the in-order
// vmcnt counter never forces a staging drain). XCD swizzle: contiguous
// 32-row band per XCD. SM=true (psf): fused softmax(225)+reflect-patch
// epilogue; raw window + bias + tap-offset table staged in dead conv LDS;
// kh-halves merged in-register via shfl_xor(32).
// launch_bounds: CT=2 -> 4 blocks/CU (VGPR cap 512, using ~245).
// IO: bf16 blocked [cb16][256 y][256 x][16 slots], slot s = ch PERM4(s).
// ---------------------------------------------------------------------------
template<bool RELU, int CT, bool SM>
__global__ __launch_bounds__(256, (CT == 2) ? 4 : 5) void conv_v10(
    const unsigned short* __restrict__ inb, const short* __restrict__ wp,
    const float* __restrict__ bias, unsigned short* __restrict__ ob,
    int C32, int Cout, int COT, int CBmax,
    const float* __restrict__ rawc, float* __restrict__ corr)
{
    int bid = blockIdx.x;
    bid = (bid & 7) * 128 + (bid >> 3);          // XCD swizzle (bijective, 1024 blocks)
    const int y  = bid >> 2;
    const int x0 = (bid & 3) << 6;
    const int t  = threadIdx.x;
    const int l  = t & 63;
    const int col = l & 31, kh = l >> 5;
    const int wv = t >> 6;
    const int ctg0 = wv * CT;

    __shared__ __align__(16) unsigned char sB[2][13824];   // 2 x (3 rows x 72 px x 64B)

    f32x16 acc[CT][2];
#pragma unroll
    for (int ct = 0; ct < CT; ++ct)
#pragma unroll
        for (int n = 0; n < 2; ++n)
#pragma unroll
            for (int i = 0; i < 16; ++i) acc[ct][n][i] = 0.f;

    int ba3[3];
#pragma unroll
    for (int dx = 0; dx < 3; ++dx) {
        int px = col + 3 + dx;
        ba3[dx] = px * 64 + ((kh ^ ((px >> 1) & 3)) << 4);   // cs -> ^32; n=1 -> +2048
    }

    // ---- staging lane constants: 4 glds issues cover 3 rows x 288 units ----
    int srcoff[4];
    bool vmask[4];
#pragma unroll
    for (int i = 0; i < 4; ++i) {
        int q = i * 256 + t;
        bool qv = q < 864;
        int row = q / 288;  if (row > 2) row = 2;
        int qr = q - row * 288;
        int px = qr >> 2, j = qr & 3;
        int u = j ^ ((px >> 1) & 3);
        int gx = x0 - 4 + px;
        int gy = y - 1 + row;
        vmask[i] = qv && ((unsigned)gx < 256u) && ((unsigned)gy < 256u);
        srcoff[i] = (((u >> 1) * 256 + gy) * 256 + gx) * 16 + (u & 1) * 8;
    }

    auto STAGE = [&](int c32, unsigned char* bufb) {
        const int coff = c32 * 2097152;          // 2 cb x 65536 px x 16 ushorts
#pragma unroll
        for (int i = 0; i < 4; ++i)
            if (vmask[i])
                glds16(inb + (srcoff[i] + coff), bufb + (i << 12) + (wv << 10));
    };

    // pre-zero both buffers (cells never written by glds must read as 0)
    for (int i = t; i < 1728; i += 256)
        *(uint4*)(&sB[0][0] + i * 16) = make_uint4(0, 0, 0, 0);
    __syncthreads();

    const bfrag* wA = (const bfrag*)wp;
    const int tstr = C32 * 2 * COT * 64;

    auto LOAD_CS = [&](bfrag (&af)[9][CT], int c32, int cs) {
        const int abase = ((c32 * 2 + cs) * COT + ctg0) * 64 + l;
#pragma unroll
        for (int tap = 0; tap < 9; ++tap)
#pragma unroll
            for (int ct = 0; ct < CT; ++ct)
                af[tap][ct] = wA[abase + ct * 64 + (size_t)tap * tstr];
    };
    auto MFMA_CS = [&](const bfrag (&af)[9][CT], const unsigned char* bufp, int csx) {
#pragma unroll
        for (int dy = 0; dy < 3; ++dy) {
            const unsigned char* rp = bufp + dy * 4608;
#pragma unroll
            for (int dx = 0; dx < 3; ++dx) {
                const int ba = ba3[dx] ^ csx;
                bfrag b0 = *(const bfrag*)(rp + ba);
                bfrag b1 = *(const bfrag*)(rp + ba + 2048);
#pragma unroll
                for (int ct = 0; ct < CT; ++ct) {
                    acc[ct][0] = __builtin_amdgcn_mfma_f32_32x32x16_bf16(af[dy * 3 + dx][ct], b0, acc[ct][0], 0, 0, 0);
                    acc[ct][1] = __builtin_amdgcn_mfma_f32_32x32x16_bf16(af[dy * 3 + dx][ct], b1, acc[ct][1], 0, 0, 0);
                }
            }
        }
    };

    bfrag afA[9][CT], afB[9][CT];
    STAGE(0, sB[0]);
    LOAD_CS(afA, 0, 0);
    __syncthreads();
    for (int c32 = 0; c32 < C32; ++c32) {
        const unsigned char* bufp = sB[c32 & 1];
        const bool more = c32 + 1 < C32;
        LOAD_CS(afB, c32, 1);                    // issue BEFORE glds (vmcnt order)
        if (more) STAGE(c32 + 1, sB[(c32 + 1) & 1]);
        MFMA_CS(afA, bufp, 0);                   // afA ready: zero vmem wait
        if (more) LOAD_CS(afA, c32 + 1, 0);      // next chunk cs0 (after glds, ok:
        MFMA_CS(afB, bufp, 32);                  //  consumed after barrier drain)
        __syncthreads();                         // drains glds + this chunk's reads
    }

    if (SM) {
        // --------- fused softmax(225) + reflect-patch epilogue ---------
        // stage raw window (15 x 80, reflect applied) + bias + tap offsets
        float* sRaw  = (float*)&sB[0][0];        // 1200 floats
        float* sBias = (float*)&sB[0][4800];     // 225 floats
        int*   sOff  = (int*)&sB[0][5700];       // 225 ints: ty*80+tx = t + 65*(t/15)
        float* red   = (float*)&sB[1][0];        // 64 px x 4 g x 3 floats
        for (int i = t; i < 1200; i += 256) {
            int r = i / 80, xx = i - r * 80;
            int gy = y + r - 7;
            gy = gy < 0 ? -gy : (gy > 255 ? 510 - gy : gy);
            int gx = x0 + xx - 7;
            gx = gx < 0 ? -gx : (gx > 255 ? 510 - gx : gx);
            sRaw[i] = rawc[gy * 256 + gx];
        }
        if (t < 225) {
            sBias[t] = bias[t];
            sOff[t]  = t + 65 * (t / 15);
        }
        __syncthreads();

        float pm[2], ps[2], pa[2];
#pragma unroll
        for (int n = 0; n < 2; ++n) {
            float m = -1e30f, s = 0.f, a = 0.f;
            const int xb = col + n * 32;         // local x (gx_local = xb + tx)
#pragma unroll
            for (int ct = 0; ct < CT; ++ct) {
                const f32x16 A = acc[ct][n];
#pragma unroll
                for (int rh = 0; rh < 2; ++rh) {
                    int cb = (ctg0 + ct) * 2 + rh;
#pragma unroll
                    for (int j = 0; j < 8; ++j) {
                        int co = cb * 16 + (j & 3) + 8 * (j >> 2) + 4 * kh;
                        if (co < 225) {
                            float lv = A[rh * 8 + j] + sBias[co];
                            float pv = sRaw[sOff[co] + xb];
                            if (lv > m + 4.f) { float rs = __expf(m - lv); s *= rs; a *= rs; m = lv; }
                            float e = __expf(lv - m);
                            s += e; a += e * pv;
                        }
                    }
                }
            }
            // in-wave kh merge (lanes l <-> l^32 hold same px, other kh half)
            float mo = __shfl_xor(m, 32), so = __shfl_xor(s, 32), ao = __shfl_xor(a, 32);
            float M = fmaxf(m, mo);
            float e0 = __expf(m - M), e1 = __expf(mo - M);
            pm[n] = M;
            ps[n] = s * e0 + so * e1;
            pa[n] = a * e0 + ao * e1;
        }
        // cross-wave merge: 4 groups (wv), px = col + n*32
        if (kh == 0) {
#pragma unroll
            for (int n = 0; n < 2; ++n) {
                int px = col + n * 32;
                red[(px * 4 + wv) * 3 + 0] = pm[n];
                red[(px * 4 + wv) * 3 + 1] = ps[n];
                red[(px * 4 + wv) * 3 + 2] = pa[n];
            }
        }
        __syncthreads();
        if (t < 64) {
            float m = red[(t * 4) * 3], s = red[(t * 4) * 3 + 1], a = red[(t * 4) * 3 + 2];
#pragma unroll
            for (int gg = 1; gg < 4; ++gg) {
                float mg = red[(t * 4 + gg) * 3], sg = red[(t * 4 + gg) * 3 + 1], ag = red[(t * 4 + gg) * 3 + 2];
                float M = fmaxf(m, mg);
                float s0 = __expf(m - M), s1 = __expf(mg - M);
                s = s * s0 + sg * s1;
                a = a * s0 + ag * s1;
                m = M;
            }
            corr[y * 256 + x0 + t] = a / s;
        }
    } else {
        // epilogue: C/D col = l&31 (px), row = (reg&3)+8*(reg>>2)+4*kh
#pragma unroll
        for (int ct = 0; ct < CT; ++ct) {
            const int ctg = ctg0 + ct;
#pragma unroll
            for (int n = 0; n < 2; ++n) {
                const int xx = x0 + col + n * 32;
                const f32x16 A = acc[ct][n];
#pragma unroll
                for (int rh = 0; rh < 2; ++rh) {
                    int cb = ctg * 2 + rh;
                    if (cb >= CBmax) continue;
                    unsigned wd[4];
#pragma unroll
                    for (int jp = 0; jp < 4; ++jp) {
                        float vv[2];
#pragma unroll
                        for (int e = 0; e < 2; ++e) {
                            int j = jp * 2 + e;
                            int co = cb * 16 + (j & 3) + 8 * (j >> 2) + 4 * kh;
                            float bv = (co < Cout) ? bias[co] : 0.f;
                            float v = A[rh * 8 + j] + bv;
                            if (RELU) v = fmaxf(v, 0.f);
                            vv[e] = v;
                        }
                        wd[jp] = packbf2(vv[0], vv[1]);
                    }
                    *(uint4*)(ob + ((((size_t)cb << 8) + y) * 256 + xx) * 16 + (kh << 3)) =
                        make_uint4(wd[0], wd[1], wd[2], wd[3]);
                }
            }
        }
    }
}

// ---------------------------------------------------------------------------
// conv_v4 (reg-staged, generic W/RS) — kept for the freq-domain convs.
// ---------------------------------------------------------------------------
template<bool RELU, bool OUT_BF16, int CT>
__global__ __launch_bounds__(256, 3) void conv_v4(
    const unsigned short* __restrict__ inb, const short* __restrict__ wp,
    const float* __restrict__ bias, void* __restrict__ outv,
    int C32, int Cout, int COT, int W, int RSg, int CBmax)
{
    const int tilesx = (W + 127) >> 7;
    const int y  = blockIdx.x / tilesx;
    const int x0 = (blockIdx.x % tilesx) << 7;
    const int t  = threadIdx.x;
    const int l  = t & 63;
    const int col = l & 31, kh = l >> 5;
    const int wv = t >> 6;
    const int wct = wv & 1, wpt = wv >> 1;
    const int ctg0 = (blockIdx.y * 2 + wct) * CT;

    __shared__ __align__(16) unsigned char sB[26112];

    f32x16 acc[CT][2];
#pragma unroll
    for (int ct = 0; ct < CT; ++ct)
#pragma unroll
        for (int n = 0; n < 2; ++n)
#pragma unroll
            for (int i = 0; i < 16; ++i) acc[ct][n][i] = 0.f;

    int ba3[3];
#pragma unroll
    for (int dx = 0; dx < 3; ++dx) {
        int px = wpt * 64 + col + 3 + dx;
        ba3[dx] = px * 64 + ((kh ^ ((px >> 1) & 3)) << 4);
    }

    const int pxm = (t & 127) + 4, thalf = t >> 7;
    const int gxm = x0 + (t & 127);
    const bool gxok = gxm < W;
    const int offm_e = pxm * 64 + ((thalf ^ ((pxm >> 1) & 3)) << 4);
    const int hr = t >> 5, hj = t & 31, hg = hj >> 3, hp = hj & 7;
    const int hslot = hp + ((hp >> 2) << 7);
    const int hgx = x0 - 4 + hslot;
    const int hoff = hr * 8704 + hslot * 64 + ((hg ^ ((hslot >> 1) & 3)) << 4);
    const int hgy = y + hr - 1;
    const bool hok = (t < 96) && ((unsigned)hgy < 256u) && ((unsigned)hgx < (unsigned)W);

    auto STAGE = [&](int c32) {
        const int cb0 = c32 << 1;
#pragma unroll
        for (int k = 0; k < 6; ++k) {
            const int r = k >> 1;
            const int cb = cb0 + (k & 1);
            const int gy = y + r - 1;
            uint4 v = make_uint4(0, 0, 0, 0);
            if (gxok && (unsigned)gy < 256u)
                v = *(const uint4*)(inb + ((((size_t)cb << 8) + gy) * RSg + gxm) * 16 + (thalf << 3));
            *(uint4*)(sB + r * 8704 + (offm_e ^ ((k & 1) << 5))) = v;
        }
        if (t < 96) {
            uint4 v = make_uint4(0, 0, 0, 0);
            if (hok) v = *(const uint4*)(inb + ((((size_t)(cb0 + (hg >> 1)) << 8) + hgy) * RSg + hgx) * 16 + ((hg & 1) << 3));
            *(uint4*)(sB + hoff) = v;
        }
    };

    const bfrag* wA = (const bfrag*)wp;
    const int tstr = C32 * 2 * COT * 64;

    STAGE(0);
    __syncthreads();
    for (int c32 = 0; c32 < C32; ++c32) {
#pragma unroll 1
        for (int cs = 0; cs < 2; ++cs) {
            const int abase = ((c32 * 2 + cs) * COT + ctg0) * 64 + l;
            const int csx = cs << 5;
#pragma unroll
            for (int dy = 0; dy < 3; ++dy) {
                bfrag af[3][CT];
#pragma unroll
                for (int dx = 0; dx < 3; ++dx)
#pragma unroll
                    for (int ct = 0; ct < CT; ++ct)
                        af[dx][ct] = wA[abase + ct * 64 + (size_t)(dy * 3 + dx) * tstr];
                const unsigned char* rp = sB + dy * 8704;
#pragma unroll
                for (int dx = 0; dx < 3; ++dx) {
                    const int ba = ba3[dx] ^ csx;
                    bfrag b0 = *(const bfrag*)(rp + ba);
                    bfrag b1 = *(const bfrag*)(rp + ba + 2048);
#pragma unroll
                    for (int ct = 0; ct < CT; ++ct) {
                        acc[ct][0] = __builtin_amdgcn_mfma_f32_32x32x16_bf16(af[dx][ct], b0, acc[ct][0], 0, 0, 0);
                        acc[ct][1] = __builtin_amdgcn_mfma_f32_32x32x16_bf16(af[dx][ct], b1, acc[ct][1], 0, 0, 0);
                    }
                }
            }
        }
        __syncthreads();
        if (c32 + 1 < C32) { STAGE(c32 + 1); __syncthreads(); }
    }

    const int xBase = x0 + wpt * 64 + col;
#pragma unroll
    for (int ct = 0; ct < CT; ++ct) {
        const int ctg = ctg0 + ct;
#pragma unroll
        for (int n = 0; n < 2; ++n) {
            int xx = xBase + n * 32;
            if (xx >= W) continue;
            const f32x16 A = acc[ct][n];
            if (OUT_BF16) {
                unsigned short* ob = (unsigned short*)outv;
#pragma unroll
                for (int rh = 0; rh < 2; ++rh) {
                    int cb = ctg * 2 + rh;
                    if (cb >= CBmax) continue;
                    unsigned wd[4];
#pragma unroll
                    for (int jp = 0; jp < 4; ++jp) {
                        float vv[2];
#pragma unroll
                        for (int e = 0; e < 2; ++e) {
                            int j = jp * 2 + e;
                            int co = cb * 16 + (j & 3) + 8 * (j >> 2) + 4 * kh;
                            float bv = (co < Cout) ? bias[co] : 0.f;
                            float v = A[rh * 8 + j] + bv;
                            if (RELU) v = fmaxf(v, 0.f);
                            vv[e] = v;
                        }
                        wd[jp] = packbf2(vv[0], vv[1]);
                    }
                    *(uint4*)(ob + ((((size_t)cb << 8) + y) * RSg + xx) * 16 + (kh << 3)) =
                        make_uint4(wd[0], wd[1], wd[2], wd[3]);
                }
            } else {
                float* of = (float*)outv;
#pragma unroll
                for (int reg = 0; reg < 16; ++reg) {
                    int co = ctg * 32 + (reg & 3) + 8 * (reg >> 2) + 4 * kh;
                    if (co < Cout) {
                        float v = A[reg] + bias[co];
                        if (RELU) v = fmaxf(v, 0.f);
                        of[(((size_t)co << 8) + y) * RSg + xx] = v;
                    }
                }
            }
        }
    }
}

// Repack fp32 OIHW -> A-frag order for 32x32x16 (PERM on ci within 16-blocks).
__global__ __launch_bounds__(256) void repack_wA(
    const float* __restrict__ w, unsigned short* __restrict__ o,
    int Cin, int C32, int Cout, int COT)
{
    int total = 9 * C32 * 2 * COT * 512;
    for (int i = blockIdx.x * 256 + threadIdx.x; i < total; i += gridDim.x * 256) {
        int j = i & 7;
        int l = (i >> 3) & 63;
        int rest = i >> 9;
        int ct = rest % COT; rest /= COT;
        int cs = rest & 1; rest >>= 1;
        int c32 = rest % C32;
        int tap = rest / C32;
        int co = ct * 32 + (l & 31);
        int s = ((l >> 5) << 3) + j;
        int ci = c32 * 32 + cs * 16 + PERM4(s);
        float v = (co < Cout && ci < Cin) ? w[((size_t)co * Cin + ci) * 9 + tap] : 0.f;
        o[i] = (unsigned short)bf16rne(v);
    }
}

// fp32 NCHW [C][256][256] -> bf16 blocked [CB][y][x][16] with PERM slots
__global__ __launch_bounds__(256) void cvt_blocked(
    const float* __restrict__ src, unsigned short* __restrict__ dst, int C)
{
    int cb = blockIdx.x >> 8;
    int y  = blockIdx.x & 255;
    int x  = threadIdx.x;
    unsigned wd[8];
#pragma unroll
    for (int q = 0; q < 8; ++q) {
        float v[2];
#pragma unroll
        for (int e = 0; e < 2; ++e) {
            int s = q * 2 + e;
            int ci = (cb << 4) + PERM4(s);
            v[e] = (ci < C) ? src[((size_t)ci * 256 + y) * 256 + x] : 0.f;
        }
        wd[q] = packbf2(v[0], v[1]);
    }
    unsigned short* dp = dst + (((size_t)cb << 16) + (y << 8) + x) * 16;
    *(uint4*)dp = make_uint4(wd[0], wd[1], wd[2], wd[3]);
    *(uint4*)(dp + 8) = make_uint4(wd[4], wd[5], wd[6], wd[7]);
}

// ---------------------------------------------------------------------------
// Refinement
// ---------------------------------------------------------------------------
__global__ __launch_bounds__(256) void repack_wr2(
    const float* __restrict__ cw2, unsigned short* __restrict__ o)
{
    int i = blockIdx.x * 256 + threadIdx.x;
    if (i >= 10240) return;
    int k = i & 31, rest = i >> 5;
    int co = rest & 15;
    int kt = (rest >> 4) % 5;
    int ch = rest / 80;
    int tap = 2 * kt + (k >= 16 ? 1 : 0), ci = k & 15;
    float v = 0.f;
    if (tap < 9) v = cw2[(((size_t)ch * 16 + co) * 16 + ci) * 9 + tap];
    o[i] = (unsigned short)bf16rne(v);
}

__global__ __launch_bounds__(256) void refine1_kernel(
    const float* __restrict__ corrected, const float* __restrict__ cw1,
    const float* __restrict__ cb1, unsigned short* __restrict__ h1b)
{
    const int c = blockIdx.x >> 8;
    const int y = blockIdx.x & 255;
    const int t = threadIdx.x;
    __shared__ float sIn[3][258];
    __shared__ float sW[144];
    __shared__ float sBv[16];
    if (t < 144) sW[t] = cw1[c * 144 + t];
    if (t >= 144 && t < 160) sBv[t - 144] = cb1[c * 16 + (t - 144)];
    for (int i = t; i < 774; i += 256) {
        int r = i / 258, xx = i % 258;
        int gy = y + r - 1, gx = xx - 1;
        sIn[r][xx] = ((unsigned)gy < 256u && (unsigned)gx < 256u)
                   ? corrected[((size_t)c * 256 + gy) * 256 + gx] : 0.f;
    }
    __syncthreads();
    float a[9];
#pragma unroll
    for (int dy = 0; dy < 3; ++dy)
#pragma unroll
        for (int dx = 0; dx < 3; ++dx) a[dy * 3 + dx] = sIn[dy][t + dx];
    unsigned short ov[16];
#pragma unroll
    for (int co = 0; co < 16; ++co) {
        float acc = sBv[co];
#pragma unroll
        for (int tap = 0; tap < 9; ++tap) acc += a[tap] * sW[co * 9 + tap];
        acc = fmaxf(acc, 0.f);
        ov[co] = (unsigned short)bf16rne(acc);
    }
    unsigned short* op = h1b + ((((size_t)c * 256 + y) * 256 + t) << 4);
    *(uint4*)op = *(uint4*)ov;
    *(uint4*)(op + 8) = *(uint4*)(ov + 8);
}

__global__ __launch_bounds__(256) void refine2_mfma(
    const unsigned short* __restrict__ h1b, const unsigned short* __restrict__ wr2,
    const float* __restrict__ cb2, unsigned short* __restrict__ h2b)
{
    const int c = blockIdx.x >> 8;
    const int y = blockIdx.x & 255;
    const int t = threadIdx.x;
    const int l15 = t & 15, lg = (t >> 4) & 3, wv = t >> 6;

    __shared__ __align__(16) unsigned char sA[3 * 258 * 32];

    for (int i = t; i < 1548; i += 256) {
        int r = i / 516, u = i % 516;
        int px = u >> 1, half = u & 1;
        int gy = y + r - 1, gx = px - 1;
        uint4 v = make_uint4(0, 0, 0, 0);
        if ((unsigned)gy < 256u && (unsigned)gx < 256u)
            v = *(const uint4*)(h1b + ((((size_t)c * 256 + gy) * 256 + gx) << 4) + (half << 3));
        *(uint4*)(sA + r * 8256 + px * 32 + ((half ^ ((px >> 2) & 1)) << 4)) = v;
    }
    __syncthreads();

    f32x4 acc[4];
#pragma unroll
    for (int n = 0; n < 4; ++n) acc[n] = (f32x4){0.f, 0.f, 0.f, 0.f};
    const bfrag* wf = (const bfrag*)(wr2 + (size_t)c * 2560);
    const int strip = wv * 64;
#pragma unroll
    for (int kt = 0; kt < 5; ++kt) {
        bfrag a = wf[(kt * 16 + l15) * 4 + lg];
        int tap1 = 2 * kt + 1; if (tap1 > 8) tap1 = 8;
        int tap = (lg < 2) ? (2 * kt) : tap1;
        int dy = tap / 3, dx = tap % 3;
#pragma unroll
        for (int n = 0; n < 4; ++n) {
            int pxs = strip + n * 16 + l15 + dx;
            bfrag b = *(const bfrag*)(sA + dy * 8256 + pxs * 32 +
                                      (((lg & 1) ^ ((pxs >> 2) & 1)) << 4));
            acc[n] = __builtin_amdgcn_mfma_f32_16x16x32_bf16(a, b, acc[n], 0, 0, 0);
        }
    }

#pragma unroll
    for (int n = 0; n < 4; ++n) {
        int px = strip + n * 16 + l15;
        unsigned short ov[4];
#pragma unroll
        for (int r = 0; r < 4; ++r) {
            int co = lg * 4 + r;
            float v = acc[n][r] + cb2[c * 16 + co];
            v = fmaxf(v, 0.f);
            ov[r] = (unsigned short)bf16rne(v);
        }
        *(ushort4*)(h2b + ((((size_t)c * 256 + y) * 256 + px) << 4) + lg * 4) = *(ushort4*)ov;
    }
}

__global__ __launch_bounds__(256) void refine3_kernel(
    const unsigned short* __restrict__ h2b, const float* __restrict__ cw3,
    const float* __restrict__ cb3, const float* __restrict__ raw,
    float* __restrict__ out)
{
    const int c = blockIdx.x >> 8;
    const int y = blockIdx.x & 255;
    const int t = threadIdx.x;
    __shared__ __align__(16) unsigned char sA[3 * 258 * 32];
    __shared__ float sW[144];
    if (t < 144) sW[t] = cw3[c * 144 + t];
    for (int i = t; i < 1548; i += 256) {
        int r = i / 516, u = i % 516;
        int px = u >> 1, half = u & 1;
        int gy = y + r - 1, gx = px - 1;
        uint4 v = make_uint4(0, 0, 0, 0);
        if ((unsigned)gy < 256u && (unsigned)gx < 256u)
            v = *(const uint4*)(h2b + ((((size_t)c * 256 + gy) * 256 + gx) << 4) + (half << 3));
        *(uint4*)(sA + r * 8256 + px * 32 + ((half ^ ((px >> 2) & 1)) << 4)) = v;
    }
    __syncthreads();
    float acc = cb3[c];
#pragma unroll
    for (int tap = 0; tap < 9; ++tap) {
        int dy = tap / 3, dx = tap % 3;
        int px = t + dx;
        const unsigned char* p = sA + dy * 8256 + px * 32;
        int sw = ((px >> 2) & 1) << 4;
        us8 h0 = *(const us8*)(p + (sw ^ 0));
        us8 h1 = *(const us8*)(p + (sw ^ 16));
#pragma unroll
        for (int j = 0; j < 8; ++j) acc += bf2f(h0[j]) * sW[j * 9 + tap];
#pragma unroll
        for (int j = 0; j < 8; ++j) acc += bf2f(h1[j]) * sW[(8 + j) * 9 + tap];
    }
    size_t idx = ((size_t)c * 256 + y) * 256 + t;
    float v = raw[idx] + acc;
    out[idx] = fminf(fmaxf(v, 0.f), 1.f);
}

// ---------------------------------------------------------------------------
// DFT kernels
// ---------------------------------------------------------------------------
__global__ __launch_bounds__(256) void rdft_row_kernel(
    const float* __restrict__ x, float2* __restrict__ z)
{
    int cy = blockIdx.x;
    __shared__ float row[256];
    __shared__ float ct[256], st[256];
    int t = threadIdx.x;
    row[t] = x[cy * 256 + t];
    float a = (2.0f * PI_F / 256.0f) * (float)t;
    ct[t] = cosf(a);
    st[t] = sinf(a);
    __syncthreads();
    if (t < 129) {
        float re = 0.f, im = 0.f;
        int idx = 0;
        for (int n = 0; n < 256; ++n) {
            float v = row[n];
            re += v * ct[idx];
            im -= v * st[idx];
            idx = (idx + t) & 255;
        }
        z[cy * 129 + t] = make_float2(re, im);
    }
}

__global__ __launch_bounds__(256) void dft_col_fwd2(
    const float2* __restrict__ z, unsigned short* __restrict__ fri16)
{
    int c  = blockIdx.x >> 8;
    int k1 = blockIdx.x & 255;
    __shared__ float ct[256], st[256];
    int t = threadIdx.x;
    float a = (2.0f * PI_F / 256.0f) * (float)t;
    ct[t] = cosf(a);
    st[t] = sinf(a);
    __syncthreads();
    if (t < 129) {
        float re = 0.f, im = 0.f;
        int idx = 0;
        for (int n1 = 0; n1 < 256; ++n1) {
            float2 zv = z[(c * 256 + n1) * 129 + t];
            float cw = ct[idx], sw = st[idx];
            re += zv.x * cw + zv.y * sw;
            im += zv.y * cw - zv.x * sw;
            idx = (idx + k1) & 255;
        }
        const float sc = 1.0f / 256.0f;
        size_t base = ((size_t)k1 * 132 + t) * 16;
        fri16[base + c]     = (unsigned short)bf16rne(re * sc);
        fri16[base + 8 + c] = (unsigned short)bf16rne(im * sc);
    }
}

__global__ __launch_bounds__(256) void dft_col_inv_kernel(
    const float* __restrict__ g, float2* __restrict__ z)
{
    int c  = blockIdx.x >> 8;
    int n1 = blockIdx.x & 255;
    __shared__ float ct[256], st[256];
    int t = threadIdx.x;
    float a = (2.0f * PI_F / 256.0f) * (float)t;
    ct[t] = cosf(a);
    st[t] = sinf(a);
    __syncthreads();
    if (t < 129) {
        float re = 0.f, im = 0.f;
        int idx = 0;
        for (int k1 = 0; k1 < 256; ++k1) {
            float gr = g[((size_t)c * 256 + k1) * 132 + t];
            float gi = g[((size_t)(4 + c) * 256 + k1) * 132 + t];
            float cw = ct[idx], sw = st[idx];
            re += gr * cw - gi * sw;
            im += gi * cw + gr * sw;
            idx = (idx + n1) & 255;
        }
        z[(c * 256 + n1) * 129 + t] = make_float2(re, im);
    }
}

__global__ __launch_bounds__(256) void irdft_row_add_kernel(
    const float2* __restrict__ z, float* __restrict__ corrected)
{
    int c  = blockIdx.x >> 8;
    int n1 = blockIdx.x & 255;
    __shared__ float2 yrow[129];
    __shared__ float ct[256], st[256];
    int t = threadIdx.x;
    if (t < 129) yrow[t] = z[(c * 256 + n1) * 129 + t];
    float a = (2.0f * PI_F / 256.0f) * (float)t;
    ct[t] = cosf(a);
    st[t] = sinf(a);
    __syncthreads();
    float acc = yrow[0].x + ((t & 1) ? -yrow[128].x : yrow[128].x);
    int idx = t;
    for (int k = 1; k <= 127; ++k) {
        float2 yv = yrow[k];
        acc += 2.0f * (yv.x * ct[idx] - yv.y * st[idx]);
        idx = (idx + t) & 255;
    }
    corrected[c * 65536 + n1 * 256 + t] += acc * (1.0f / 256.0f);
}

// ---------------------------------------------------------------------------
extern "C" void kernel_launch(void* const* d_in, const int* in_sizes, int n_in,
                              void* d_out, int out_size, void* d_ws, size_t ws_size,
                              hipStream_t stream)
{
    const float* raw = (const float*)d_in[0];
    const float* ab  = (const float*)d_in[1];
    const float* pw1 = (const float*)d_in[2];  const float* pb1 = (const float*)d_in[3];
    const float* pw2 = (const float*)d_in[4];  const float* pb2 = (const float*)d_in[5];
    const float* pw3 = (const float*)d_in[6];  const float* pb3 = (const float*)d_in[7];
    const float* fw1 = (const float*)d_in[8];  const float* fb1 = (const float*)d_in[9];
    const float* fw2 = (const float*)d_in[10]; const float* fb2 = (const float*)d_in[11];
    const float* fw3 = (const float*)d_in[12]; const float* fb3 = (const float*)d_in[13];
    const float* cw1 = (const float*)d_in[14]; const float* cb1 = (const float*)d_in[15];
    const float* cw2 = (const float*)d_in[16]; const float* cb2 = (const float*)d_in[17];
    const float* cw3 = (const float*)d_in[18]; const float* cb3 = (const float*)d_in[19];
    float* out = (float*)d_out;

    char* B = (char*)d_ws;
    unsigned short* h1b     = (unsigned short*)(B);              // 33,554,432 B (16 cb)
    unsigned short* h2b     = (unsigned short*)(B + 33554432);   // 16,777,216 B (8 cb)
    unsigned short* h1r     = (unsigned short*)(B + 33554432);   // alias (after psf)
    unsigned short* h2r     = (unsigned short*)(B + 41943040);
    float* corrected = (float*)(B + 50331648);                   // 1,048,576 B
    float2* zbuf     = (float2*)(B + 51380224);                  // 2,113,536 B
    unsigned short* fri16 = (unsigned short*)(B + 53493760);     // 2,162,688 B (2 cb, RS 132)
    unsigned short* g1b   = (unsigned short*)(B + 55656448);     // 4,325,376 B (4 cb)
    unsigned short* g2b   = (unsigned short*)(B + 59981824);     // 4,325,376 B
    float* gf        = (float*)(B + 64307200);                   // 1,081,344 B
    unsigned short* rw1  = (unsigned short*)(B + 65388544);      // 589,824 B
    unsigned short* rw2  = (unsigned short*)(B + 65978368);      // 589,824 B
    unsigned short* rw3  = (unsigned short*)(B + 66568192);      // 4 x 589,824 B
    unsigned short* rwf1 = (unsigned short*)(B + 68927488);      // 36,864 B
    unsigned short* rwf2 = (unsigned short*)(B + 68964352);      // 73,728 B
    unsigned short* rwf3 = (unsigned short*)(B + 69038080);      // 73,728 B
    unsigned short* wr2r = (unsigned short*)(B + 69111808);      // 20,480 B
    unsigned short* ab16 = (unsigned short*)(B + 69132288);      // 16,777,216 B

    dim3 blk(256);

    // weight repacks + input conversion
    repack_wA<<<512, blk, 0, stream>>>(pw1, rw1, 128, 4, 256, 8);
    repack_wA<<<512, blk, 0, stream>>>(pw2, rw2, 256, 8, 128, 4);
    for (int c = 0; c < 4; ++c)
        repack_wA<<<512, blk, 0, stream>>>(
            pw3 + (size_t)c * 225 * 128 * 9, rw3 + (size_t)c * 294912, 128, 4, 225, 8);
    repack_wA<<<64, blk, 0, stream>>>(fw1, rwf1, 8, 1, 64, 2);
    repack_wA<<<128, blk, 0, stream>>>(fw2, rwf2, 64, 2, 64, 2);
    repack_wA<<<128, blk, 0, stream>>>(fw3, rwf3, 64, 2, 8, 2);
    repack_wr2<<<40, blk, 0, stream>>>(cw2, wr2r);
    cvt_blocked<<<2048, blk, 0, stream>>>(ab, ab16, 128);

    // conv1: ab16(128) -> h1b(256), relu   [block = 256co x 64px, CT=2]
    conv_v10<true, 2, false><<<1024, blk, 0, stream>>>(
        ab16, (const short*)rw1, pb1, h1b, 4, 256, 8, 16, nullptr, nullptr);
    // conv2: h1b(256) -> h2b(128), relu    [block = 128co x 64px, CT=1]
    conv_v10<true, 1, false><<<1024, blk, 0, stream>>>(
        h1b, (const short*)rw2, pb2, h2b, 8, 128, 4, 8, nullptr, nullptr);
    // psf conv with FUSED softmax+patch epilogue, per image channel
    for (int c = 0; c < 4; ++c) {
        conv_v10<false, 2, true><<<1024, blk, 0, stream>>>(
            h2b, (const short*)(rw3 + (size_t)c * 294912), pb3 + c * 225, h1b,
            4, 225, 8, 15, raw + c * 65536, corrected + c * 65536);
    }
    // forward rfft2 (ortho)
    rdft_row_kernel<<<1024, blk, 0, stream>>>(corrected, zbuf);
    hipMemsetAsync(fri16, 0, 2162688, stream);
    dft_col_fwd2<<<1024, blk, 0, stream>>>(zbuf, fri16);
    // freq-domain convs (W=129, RS=132)
    conv_v4<true, true, 1><<<dim3(512, 1), blk, 0, stream>>>(
        fri16, (const short*)rwf1, fb1, g1b, 1, 64, 2, 129, 132, 4);
    conv_v4<true, true, 1><<<dim3(512, 1), blk, 0, stream>>>(
        g1b, (const short*)rwf2, fb2, g2b, 2, 64, 2, 129, 132, 4);
    conv_v4<false, false, 1><<<dim3(512, 1), blk, 0, stream>>>(
        g2b, (const short*)rwf3, fb3, gf, 2, 8, 2, 129, 132, 0);
    // inverse irfft2 (ortho), accumulate into corrected
    dft_col_inv_kernel<<<1024, blk, 0, stream>>>(gf, zbuf);
    irdft_row_add_kernel<<<1024, blk, 0, stream>>>(zbuf, corrected);
    // per-channel refinement, fused final clip
    refine1_kernel<<<1024, blk, 0, stream>>>(corrected, cw1, cb1, h1r);
    refine2_mfma<<<1024, blk, 0, stream>>>(h1r, wr2r, cb2, h2r);
    refine3_kernel<<<1024, blk, 0, stream>>>(h2r, cw3, cb3, raw, out);
}

// Round 17
// 472.064 us; speedup vs baseline: 2.3218x; 2.3218x over previous
//
#include <hip/hip_runtime.h>
#include <hip/hip_bf16.h>
#include <math.h>

#define PI_F 3.14159265358979323846f
// ci16 permutation (involution, swaps bits 2<->3): storage slot s holds channel PERM4(s)
#define PERM4(s) ((((s)&3)) + 8*(((s)>>2)&1) + 4*((s)>>3))

typedef short bfrag __attribute__((ext_vector_type(8)));   // 8 bf16 (4 VGPR)
typedef float f32x4 __attribute__((ext_vector_type(4)));
typedef float f32x16 __attribute__((ext_vector_type(16)));
typedef unsigned short us8 __attribute__((ext_vector_type(8)));

__device__ inline unsigned bf16rne(float x) {
    unsigned u = __builtin_bit_cast(unsigned, x);
    return (u + 0x7fffu + ((u >> 16) & 1u)) >> 16;
}
__device__ inline unsigned packbf2(float a, float b) {
    return bf16rne(a) | (bf16rne(b) << 16);
}
__device__ inline float bf2f(unsigned short u) {
    return __builtin_bit_cast(float, (unsigned)u << 16);
}
__device__ inline void glds16(const unsigned short* g, unsigned char* l) {
    __builtin_amdgcn_global_load_lds(
        (const __attribute__((address_space(1))) unsigned int*)g,
        (__attribute__((address_space(3))) unsigned int*)l, 16, 0, 0);
}

// ---------------------------------------------------------------------------
// conv_v9 (r15 known-good structure): MFMA implicit-GEMM 3x3 conv, pad 1,
// 32x32x16 bf16, W=256 ONLY. Double-buffered LDS + glds staging; cs0/dy0
// A-frags loaded BEFORE the STAGE(c+1) issue. XCD swizzle: contiguous 32-row
// band per XCD. SM=true (psf): fused softmax(225)+reflect-patch epilogue;
// raw window + bias + tap-offset table in dead conv LDS; kh-halves merged
// in-register via shfl_xor(32). DO NOT enlarge fragment arrays (r13/r16:
// anything past ~60 VGPR of lambda-passed arrays spills to scratch).
// IO: bf16 blocked [cb16][256 y][256 x][16 slots], slot s = ch PERM4(s).
// ---------------------------------------------------------------------------
template<bool RELU, int CT, bool SM>
__global__ __launch_bounds__(256, (CT == 2) ? 4 : 5) void conv_v9(
    const unsigned short* __restrict__ inb, const short* __restrict__ wp,
    const float* __restrict__ bias, unsigned short* __restrict__ ob,
    int C32, int Cout, int COT, int CBmax,
    const float* __restrict__ rawc, float* __restrict__ corr)
{
    int bid = blockIdx.x;
    bid = (bid & 7) * 128 + (bid >> 3);          // XCD swizzle (bijective, 1024 blocks)
    const int y  = bid >> 2;
    const int x0 = (bid & 3) << 6;
    const int t  = threadIdx.x;
    const int l  = t & 63;
    const int col = l & 31, kh = l >> 5;
    const int wv = t >> 6;
    const int ctg0 = wv * CT;

    __shared__ __align__(16) unsigned char sB[2][13824];   // 2 x (3 rows x 72 px x 64B)

    f32x16 acc[CT][2];
#pragma unroll
    for (int ct = 0; ct < CT; ++ct)
#pragma unroll
        for (int n = 0; n < 2; ++n)
#pragma unroll
            for (int i = 0; i < 16; ++i) acc[ct][n][i] = 0.f;

    int ba3[3];
#pragma unroll
    for (int dx = 0; dx < 3; ++dx) {
        int px = col + 3 + dx;
        ba3[dx] = px * 64 + ((kh ^ ((px >> 1) & 3)) << 4);   // cs -> ^32; n=1 -> +2048
    }

    // ---- staging lane constants: 4 glds issues cover 3 rows x 288 units ----
    int srcoff[4];
    bool vmask[4];
#pragma unroll
    for (int i = 0; i < 4; ++i) {
        int q = i * 256 + t;
        bool qv = q < 864;
        int row = q / 288;  if (row > 2) row = 2;
        int qr = q - row * 288;
        int px = qr >> 2, j = qr & 3;
        int u = j ^ ((px >> 1) & 3);
        int gx = x0 - 4 + px;
        int gy = y - 1 + row;
        vmask[i] = qv && ((unsigned)gx < 256u) && ((unsigned)gy < 256u);
        srcoff[i] = (((u >> 1) * 256 + gy) * 256 + gx) * 16 + (u & 1) * 8;
    }

    auto STAGE = [&](int c32, unsigned char* bufb) {
        const int coff = c32 * 2097152;          // 2 cb x 65536 px x 16 ushorts
#pragma unroll
        for (int i = 0; i < 4; ++i)
            if (vmask[i])
                glds16(inb + (srcoff[i] + coff), bufb + (i << 12) + (wv << 10));
    };

    // pre-zero both buffers (cells never written by glds must read as 0)
    for (int i = t; i < 1728; i += 256)
        *(uint4*)(&sB[0][0] + i * 16) = make_uint4(0, 0, 0, 0);
    __syncthreads();

    const bfrag* wA = (const bfrag*)wp;
    const int tstr = C32 * 2 * COT * 64;

    auto LOAD_AF = [&](bfrag (&af)[3][CT], int abase, int dy) {
#pragma unroll
        for (int dx = 0; dx < 3; ++dx)
#pragma unroll
            for (int ct = 0; ct < CT; ++ct)
                af[dx][ct] = wA[abase + ct * 64 + (size_t)(dy * 3 + dx) * tstr];
    };
    auto MFMA_DY = [&](const bfrag (&af)[3][CT], const unsigned char* rp, int csx) {
#pragma unroll
        for (int dx = 0; dx < 3; ++dx) {
            const int ba = ba3[dx] ^ csx;
            bfrag b0 = *(const bfrag*)(rp + ba);
            bfrag b1 = *(const bfrag*)(rp + ba + 2048);
#pragma unroll
            for (int ct = 0; ct < CT; ++ct) {
                acc[ct][0] = __builtin_amdgcn_mfma_f32_32x32x16_bf16(af[dx][ct], b0, acc[ct][0], 0, 0, 0);
                acc[ct][1] = __builtin_amdgcn_mfma_f32_32x32x16_bf16(af[dx][ct], b1, acc[ct][1], 0, 0, 0);
            }
        }
    };

    STAGE(0, sB[0]);
    __syncthreads();
    for (int c32 = 0; c32 < C32; ++c32) {
        const unsigned char* bufp = sB[c32 & 1];
        const int ab0 = (c32 * 2 * COT + ctg0) * 64 + l;
        const int ab1 = ((c32 * 2 + 1) * COT + ctg0) * 64 + l;
        bfrag af0[3][CT];
        LOAD_AF(af0, ab0, 0);                              // BEFORE stage issue
        if (c32 + 1 < C32) STAGE(c32 + 1, sB[(c32 + 1) & 1]);
        MFMA_DY(af0, bufp, 0);                             // cs=0, dy=0
#pragma unroll
        for (int dy = 1; dy < 3; ++dy) {                   // cs=0, dy=1..2
            bfrag af[3][CT];
            LOAD_AF(af, ab0, dy);
            MFMA_DY(af, bufp + dy * 4608, 0);
        }
#pragma unroll
        for (int dy = 0; dy < 3; ++dy) {                   // cs=1, dy=0..2
            bfrag af[3][CT];
            LOAD_AF(af, ab1, dy);
            MFMA_DY(af, bufp + dy * 4608, 32);
        }
        __syncthreads();   // drains next-stage glds + this chunk's LDS reads
    }

    if (SM) {
        // --------- fused softmax(225) + reflect-patch epilogue ---------
        // stage raw window (15 x 80, reflect applied) + bias + tap offsets
        float* sRaw  = (float*)&sB[0][0];        // 1200 floats
        float* sBias = (float*)&sB[0][4800];     // 225 floats
        int*   sOff  = (int*)&sB[0][5700];       // 225 ints: ty*80+tx = t + 65*(t/15)
        float* red   = (float*)&sB[1][0];        // 64 px x 4 g x 3 floats
        for (int i = t; i < 1200; i += 256) {
            int r = i / 80, xx = i - r * 80;
            int gy = y + r - 7;
            gy = gy < 0 ? -gy : (gy > 255 ? 510 - gy : gy);
            int gx = x0 + xx - 7;
            gx = gx < 0 ? -gx : (gx > 255 ? 510 - gx : gx);
            sRaw[i] = rawc[gy * 256 + gx];
        }
        if (t < 225) {
            sBias[t] = bias[t];
            sOff[t]  = t + 65 * (t / 15);
        }
        __syncthreads();

        float pm[2], ps[2], pa[2];
#pragma unroll
        for (int n = 0; n < 2; ++n) {
            float m = -1e30f, s = 0.f, a = 0.f;
            const int xb = col + n * 32;         // local x (gx_local = xb + tx)
#pragma unroll
            for (int ct = 0; ct < CT; ++ct) {
                const f32x16 A = acc[ct][n];
#pragma unroll
                for (int rh = 0; rh < 2; ++rh) {
                    int cb = (ctg0 + ct) * 2 + rh;
#pragma unroll
                    for (int j = 0; j < 8; ++j) {
                        int co = cb * 16 + (j & 3) + 8 * (j >> 2) + 4 * kh;
                        if (co < 225) {
                            float lv = A[rh * 8 + j] + sBias[co];
                            float pv = sRaw[sOff[co] + xb];
                            if (lv > m + 4.f) { float rs = __expf(m - lv); s *= rs; a *= rs; m = lv; }
                            float e = __expf(lv - m);
                            s += e; a += e * pv;
                        }
                    }
                }
            }
            // in-wave kh merge (lanes l <-> l^32 hold same px, other kh half)
            float mo = __shfl_xor(m, 32), so = __shfl_xor(s, 32), ao = __shfl_xor(a, 32);
            float M = fmaxf(m, mo);
            float e0 = __expf(m - M), e1 = __expf(mo - M);
            pm[n] = M;
            ps[n] = s * e0 + so * e1;
            pa[n] = a * e0 + ao * e1;
        }
        // cross-wave merge: 4 groups (wv), px = col + n*32
        if (kh == 0) {
#pragma unroll
            for (int n = 0; n < 2; ++n) {
                int px = col + n * 32;
                red[(px * 4 + wv) * 3 + 0] = pm[n];
                red[(px * 4 + wv) * 3 + 1] = ps[n];
                red[(px * 4 + wv) * 3 + 2] = pa[n];
            }
        }
        __syncthreads();
        if (t < 64) {
            float m = red[(t * 4) * 3], s = red[(t * 4) * 3 + 1], a = red[(t * 4) * 3 + 2];
#pragma unroll
            for (int gg = 1; gg < 4; ++gg) {
                float mg = red[(t * 4 + gg) * 3], sg = red[(t * 4 + gg) * 3 + 1], ag = red[(t * 4 + gg) * 3 + 2];
                float M = fmaxf(m, mg);
                float s0 = __expf(m - M), s1 = __expf(mg - M);
                s = s * s0 + sg * s1;
                a = a * s0 + ag * s1;
                m = M;
            }
            corr[y * 256 + x0 + t] = a / s;
        }
    } else {
        // epilogue: C/D col = l&31 (px), row = (reg&3)+8*(reg>>2)+4*kh
#pragma unroll
        for (int ct = 0; ct < CT; ++ct) {
            const int ctg = ctg0 + ct;
#pragma unroll
            for (int n = 0; n < 2; ++n) {
                const int xx = x0 + col + n * 32;
                const f32x16 A = acc[ct][n];
#pragma unroll
                for (int rh = 0; rh < 2; ++rh) {
                    int cb = ctg * 2 + rh;
                    if (cb >= CBmax) continue;
                    unsigned wd[4];
#pragma unroll
                    for (int jp = 0; jp < 4; ++jp) {
                        float vv[2];
#pragma unroll
                        for (int e = 0; e < 2; ++e) {
                            int j = jp * 2 + e;
                            int co = cb * 16 + (j & 3) + 8 * (j >> 2) + 4 * kh;
                            float bv = (co < Cout) ? bias[co] : 0.f;
                            float v = A[rh * 8 + j] + bv;
                            if (RELU) v = fmaxf(v, 0.f);
                            vv[e] = v;
                        }
                        wd[jp] = packbf2(vv[0], vv[1]);
                    }
                    *(uint4*)(ob + ((((size_t)cb << 8) + y) * 256 + xx) * 16 + (kh << 3)) =
                        make_uint4(wd[0], wd[1], wd[2], wd[3]);
                }
            }
        }
    }
}

// ---------------------------------------------------------------------------
// conv_v4 (reg-staged, generic W/RS) — kept for the freq-domain convs.
// ---------------------------------------------------------------------------
template<bool RELU, bool OUT_BF16, int CT>
__global__ __launch_bounds__(256, 3) void conv_v4(
    const unsigned short* __restrict__ inb, const short* __restrict__ wp,
    const float* __restrict__ bias, void* __restrict__ outv,
    int C32, int Cout, int COT, int W, int RSg, int CBmax)
{
    const int tilesx = (W + 127) >> 7;
    const int y  = blockIdx.x / tilesx;
    const int x0 = (blockIdx.x % tilesx) << 7;
    const int t  = threadIdx.x;
    const int l  = t & 63;
    const int col = l & 31, kh = l >> 5;
    const int wv = t >> 6;
    const int wct = wv & 1, wpt = wv >> 1;
    const int ctg0 = (blockIdx.y * 2 + wct) * CT;

    __shared__ __align__(16) unsigned char sB[26112];

    f32x16 acc[CT][2];
#pragma unroll
    for (int ct = 0; ct < CT; ++ct)
#pragma unroll
        for (int n = 0; n < 2; ++n)
#pragma unroll
            for (int i = 0; i < 16; ++i) acc[ct][n][i] = 0.f;

    int ba3[3];
#pragma unroll
    for (int dx = 0; dx < 3; ++dx) {
        int px = wpt * 64 + col + 3 + dx;
        ba3[dx] = px * 64 + ((kh ^ ((px >> 1) & 3)) << 4);
    }

    const int pxm = (t & 127) + 4, thalf = t >> 7;
    const int gxm = x0 + (t & 127);
    const bool gxok = gxm < W;
    const int offm_e = pxm * 64 + ((thalf ^ ((pxm >> 1) & 3)) << 4);
    const int hr = t >> 5, hj = t & 31, hg = hj >> 3, hp = hj & 7;
    const int hslot = hp + ((hp >> 2) << 7);
    const int hgx = x0 - 4 + hslot;
    const int hoff = hr * 8704 + hslot * 64 + ((hg ^ ((hslot >> 1) & 3)) << 4);
    const int hgy = y + hr - 1;
    const bool hok = (t < 96) && ((unsigned)hgy < 256u) && ((unsigned)hgx < (unsigned)W);

    auto STAGE = [&](int c32) {
        const int cb0 = c32 << 1;
#pragma unroll
        for (int k = 0; k < 6; ++k) {
            const int r = k >> 1;
            const int cb = cb0 + (k & 1);
            const int gy = y + r - 1;
            uint4 v = make_uint4(0, 0, 0, 0);
            if (gxok && (unsigned)gy < 256u)
                v = *(const uint4*)(inb + ((((size_t)cb << 8) + gy) * RSg + gxm) * 16 + (thalf << 3));
            *(uint4*)(sB + r * 8704 + (offm_e ^ ((k & 1) << 5))) = v;
        }
        if (t < 96) {
            uint4 v = make_uint4(0, 0, 0, 0);
            if (hok) v = *(const uint4*)(inb + ((((size_t)(cb0 + (hg >> 1)) << 8) + hgy) * RSg + hgx) * 16 + ((hg & 1) << 3));
            *(uint4*)(sB + hoff) = v;
        }
    };

    const bfrag* wA = (const bfrag*)wp;
    const int tstr = C32 * 2 * COT * 64;

    STAGE(0);
    __syncthreads();
    for (int c32 = 0; c32 < C32; ++c32) {
#pragma unroll 1
        for (int cs = 0; cs < 2; ++cs) {
            const int abase = ((c32 * 2 + cs) * COT + ctg0) * 64 + l;
            const int csx = cs << 5;
#pragma unroll
            for (int dy = 0; dy < 3; ++dy) {
                bfrag af[3][CT];
#pragma unroll
                for (int dx = 0; dx < 3; ++dx)
#pragma unroll
                    for (int ct = 0; ct < CT; ++ct)
                        af[dx][ct] = wA[abase + ct * 64 + (size_t)(dy * 3 + dx) * tstr];
                const unsigned char* rp = sB + dy * 8704;
#pragma unroll
                for (int dx = 0; dx < 3; ++dx) {
                    const int ba = ba3[dx] ^ csx;
                    bfrag b0 = *(const bfrag*)(rp + ba);
                    bfrag b1 = *(const bfrag*)(rp + ba + 2048);
#pragma unroll
                    for (int ct = 0; ct < CT; ++ct) {
                        acc[ct][0] = __builtin_amdgcn_mfma_f32_32x32x16_bf16(af[dx][ct], b0, acc[ct][0], 0, 0, 0);
                        acc[ct][1] = __builtin_amdgcn_mfma_f32_32x32x16_bf16(af[dx][ct], b1, acc[ct][1], 0, 0, 0);
                    }
                }
            }
        }
        __syncthreads();
        if (c32 + 1 < C32) { STAGE(c32 + 1); __syncthreads(); }
    }

    const int xBase = x0 + wpt * 64 + col;
#pragma unroll
    for (int ct = 0; ct < CT; ++ct) {
        const int ctg = ctg0 + ct;
#pragma unroll
        for (int n = 0; n < 2; ++n) {
            int xx = xBase + n * 32;
            if (xx >= W) continue;
            const f32x16 A = acc[ct][n];
            if (OUT_BF16) {
                unsigned short* ob = (unsigned short*)outv;
#pragma unroll
                for (int rh = 0; rh < 2; ++rh) {
                    int cb = ctg * 2 + rh;
                    if (cb >= CBmax) continue;
                    unsigned wd[4];
#pragma unroll
                    for (int jp = 0; jp < 4; ++jp) {
                        float vv[2];
#pragma unroll
                        for (int e = 0; e < 2; ++e) {
                            int j = jp * 2 + e;
                            int co = cb * 16 + (j & 3) + 8 * (j >> 2) + 4 * kh;
                            float bv = (co < Cout) ? bias[co] : 0.f;
                            float v = A[rh * 8 + j] + bv;
                            if (RELU) v = fmaxf(v, 0.f);
                            vv[e] = v;
                        }
                        wd[jp] = packbf2(vv[0], vv[1]);
                    }
                    *(uint4*)(ob + ((((size_t)cb << 8) + y) * RSg + xx) * 16 + (kh << 3)) =
                        make_uint4(wd[0], wd[1], wd[2], wd[3]);
                }
            } else {
                float* of = (float*)outv;
#pragma unroll
                for (int reg = 0; reg < 16; ++reg) {
                    int co = ctg * 32 + (reg & 3) + 8 * (reg >> 2) + 4 * kh;
                    if (co < Cout) {
                        float v = A[reg] + bias[co];
                        if (RELU) v = fmaxf(v, 0.f);
                        of[(((size_t)co << 8) + y) * RSg + xx] = v;
                    }
                }
            }
        }
    }
}

// Repack fp32 OIHW -> A-frag order for 32x32x16 (PERM on ci within 16-blocks).
__global__ __launch_bounds__(256) void repack_wA(
    const float* __restrict__ w, unsigned short* __restrict__ o,
    int Cin, int C32, int Cout, int COT)
{
    int total = 9 * C32 * 2 * COT * 512;
    for (int i = blockIdx.x * 256 + threadIdx.x; i < total; i += gridDim.x * 256) {
        int j = i & 7;
        int l = (i >> 3) & 63;
        int rest = i >> 9;
        int ct = rest % COT; rest /= COT;
        int cs = rest & 1; rest >>= 1;
        int c32 = rest % C32;
        int tap = rest / C32;
        int co = ct * 32 + (l & 31);
        int s = ((l >> 5) << 3) + j;
        int ci = c32 * 32 + cs * 16 + PERM4(s);
        float v = (co < Cout && ci < Cin) ? w[((size_t)co * Cin + ci) * 9 + tap] : 0.f;
        o[i] = (unsigned short)bf16rne(v);
    }
}

// fp32 NCHW [C][256][256] -> bf16 blocked [CB][y][x][16] with PERM slots
__global__ __launch_bounds__(256) void cvt_blocked(
    const float* __restrict__ src, unsigned short* __restrict__ dst, int C)
{
    int cb = blockIdx.x >> 8;
    int y  = blockIdx.x & 255;
    int x  = threadIdx.x;
    unsigned wd[8];
#pragma unroll
    for (int q = 0; q < 8; ++q) {
        float v[2];
#pragma unroll
        for (int e = 0; e < 2; ++e) {
            int s = q * 2 + e;
            int ci = (cb << 4) + PERM4(s);
            v[e] = (ci < C) ? src[((size_t)ci * 256 + y) * 256 + x] : 0.f;
        }
        wd[q] = packbf2(v[0], v[1]);
    }
    unsigned short* dp = dst + (((size_t)cb << 16) + (y << 8) + x) * 16;
    *(uint4*)dp = make_uint4(wd[0], wd[1], wd[2], wd[3]);
    *(uint4*)(dp + 8) = make_uint4(wd[4], wd[5], wd[6], wd[7]);
}

// ---------------------------------------------------------------------------
// Refinement
// ---------------------------------------------------------------------------
__global__ __launch_bounds__(256) void repack_wr2(
    const float* __restrict__ cw2, unsigned short* __restrict__ o)
{
    int i = blockIdx.x * 256 + threadIdx.x;
    if (i >= 10240) return;
    int k = i & 31, rest = i >> 5;
    int co = rest & 15;
    int kt = (rest >> 4) % 5;
    int ch = rest / 80;
    int tap = 2 * kt + (k >= 16 ? 1 : 0), ci = k & 15;
    float v = 0.f;
    if (tap < 9) v = cw2[(((size_t)ch * 16 + co) * 16 + ci) * 9 + tap];
    o[i] = (unsigned short)bf16rne(v);
}

__global__ __launch_bounds__(256) void refine1_kernel(
    const float* __restrict__ corrected, const float* __restrict__ cw1,
    const float* __restrict__ cb1, unsigned short* __restrict__ h1b)
{
    const int c = blockIdx.x >> 8;
    const int y = blockIdx.x & 255;
    const int t = threadIdx.x;
    __shared__ float sIn[3][258];
    __shared__ float sW[144];
    __shared__ float sBv[16];
    if (t < 144) sW[t] = cw1[c * 144 + t];
    if (t >= 144 && t < 160) sBv[t - 144] = cb1[c * 16 + (t - 144)];
    for (int i = t; i < 774; i += 256) {
        int r = i / 258, xx = i % 258;
        int gy = y + r - 1, gx = xx - 1;
        sIn[r][xx] = ((unsigned)gy < 256u && (unsigned)gx < 256u)
                   ? corrected[((size_t)c * 256 + gy) * 256 + gx] : 0.f;
    }
    __syncthreads();
    float a[9];
#pragma unroll
    for (int dy = 0; dy < 3; ++dy)
#pragma unroll
        for (int dx = 0; dx < 3; ++dx) a[dy * 3 + dx] = sIn[dy][t + dx];
    unsigned short ov[16];
#pragma unroll
    for (int co = 0; co < 16; ++co) {
        float acc = sBv[co];
#pragma unroll
        for (int tap = 0; tap < 9; ++tap) acc += a[tap] * sW[co * 9 + tap];
        acc = fmaxf(acc, 0.f);
        ov[co] = (unsigned short)bf16rne(acc);
    }
    unsigned short* op = h1b + ((((size_t)c * 256 + y) * 256 + t) << 4);
    *(uint4*)op = *(uint4*)ov;
    *(uint4*)(op + 8) = *(uint4*)(ov + 8);
}

__global__ __launch_bounds__(256) void refine2_mfma(
    const unsigned short* __restrict__ h1b, const unsigned short* __restrict__ wr2,
    const float* __restrict__ cb2, unsigned short* __restrict__ h2b)
{
    const int c = blockIdx.x >> 8;
    const int y = blockIdx.x & 255;
    const int t = threadIdx.x;
    const int l15 = t & 15, lg = (t >> 4) & 3, wv = t >> 6;

    __shared__ __align__(16) unsigned char sA[3 * 258 * 32];

    for (int i = t; i < 1548; i += 256) {
        int r = i / 516, u = i % 516;
        int px = u >> 1, half = u & 1;
        int gy = y + r - 1, gx = px - 1;
        uint4 v = make_uint4(0, 0, 0, 0);
        if ((unsigned)gy < 256u && (unsigned)gx < 256u)
            v = *(const uint4*)(h1b + ((((size_t)c * 256 + gy) * 256 + gx) << 4) + (half << 3));
        *(uint4*)(sA + r * 8256 + px * 32 + ((half ^ ((px >> 2) & 1)) << 4)) = v;
    }
    __syncthreads();

    f32x4 acc[4];
#pragma unroll
    for (int n = 0; n < 4; ++n) acc[n] = (f32x4){0.f, 0.f, 0.f, 0.f};
    const bfrag* wf = (const bfrag*)(wr2 + (size_t)c * 2560);
    const int strip = wv * 64;
#pragma unroll
    for (int kt = 0; kt < 5; ++kt) {
        bfrag a = wf[(kt * 16 + l15) * 4 + lg];
        int tap1 = 2 * kt + 1; if (tap1 > 8) tap1 = 8;
        int tap = (lg < 2) ? (2 * kt) : tap1;
        int dy = tap / 3, dx = tap % 3;
#pragma unroll
        for (int n = 0; n < 4; ++n) {
            int pxs = strip + n * 16 + l15 + dx;
            bfrag b = *(const bfrag*)(sA + dy * 8256 + pxs * 32 +
                                      (((lg & 1) ^ ((pxs >> 2) & 1)) << 4));
            acc[n] = __builtin_amdgcn_mfma_f32_16x16x32_bf16(a, b, acc[n], 0, 0, 0);
        }
    }

#pragma unroll
    for (int n = 0; n < 4; ++n) {
        int px = strip + n * 16 + l15;
        unsigned short ov[4];
#pragma unroll
        for (int r = 0; r < 4; ++r) {
            int co = lg * 4 + r;
            float v = acc[n][r] + cb2[c * 16 + co];
            v = fmaxf(v, 0.f);
            ov[r] = (unsigned short)bf16rne(v);
        }
        *(ushort4*)(h2b + ((((size_t)c * 256 + y) * 256 + px) << 4) + lg * 4) = *(ushort4*)ov;
    }
}

__global__ __launch_bounds__(256) void refine3_kernel(
    const unsigned short* __restrict__ h2b, const float* __restrict__ cw3,
    const float* __restrict__ cb3, const float* __restrict__ raw,
    float* __restrict__ out)
{
    const int c = blockIdx.x >> 8;
    const int y = blockIdx.x & 255;
    const int t = threadIdx.x;
    __shared__ __align__(16) unsigned char sA[3 * 258 * 32];
    __shared__ float sW[144];
    if (t < 144) sW[t] = cw3[c * 144 + t];
    for (int i = t; i < 1548; i += 256) {
        int r = i / 516, u = i % 516;
        int px = u >> 1, half = u & 1;
        int gy = y + r - 1, gx = px - 1;
        uint4 v = make_uint4(0, 0, 0, 0);
        if ((unsigned)gy < 256u && (unsigned)gx < 256u)
            v = *(const uint4*)(h2b + ((((size_t)c * 256 + gy) * 256 + gx) << 4) + (half << 3));
        *(uint4*)(sA + r * 8256 + px * 32 + ((half ^ ((px >> 2) & 1)) << 4)) = v;
    }
    __syncthreads();
    float acc = cb3[c];
#pragma unroll
    for (int tap = 0; tap < 9; ++tap) {
        int dy = tap / 3, dx = tap % 3;
        int px = t + dx;
        const unsigned char* p = sA + dy * 8256 + px * 32;
        int sw = ((px >> 2) & 1) << 4;
        us8 h0 = *(const us8*)(p + (sw ^ 0));
        us8 h1 = *(const us8*)(p + (sw ^ 16));
#pragma unroll
        for (int j = 0; j < 8; ++j) acc += bf2f(h0[j]) * sW[j * 9 + tap];
#pragma unroll
        for (int j = 0; j < 8; ++j) acc += bf2f(h1[j]) * sW[(8 + j) * 9 + tap];
    }
    size_t idx = ((size_t)c * 256 + y) * 256 + t;
    float v = raw[idx] + acc;
    out[idx] = fminf(fmaxf(v, 0.f), 1.f);
}

// ---------------------------------------------------------------------------
// DFT kernels
// ---------------------------------------------------------------------------
__global__ __launch_bounds__(256) void rdft_row_kernel(
    const float* __restrict__ x, float2* __restrict__ z)
{
    int cy = blockIdx.x;
    __shared__ float row[256];
    __shared__ float ct[256], st[256];
    int t = threadIdx.x;
    row[t] = x[cy * 256 + t];
    float a = (2.0f * PI_F / 256.0f) * (float)t;
    ct[t] = cosf(a);
    st[t] = sinf(a);
    __syncthreads();
    if (t < 129) {
        float re = 0.f, im = 0.f;
        int idx = 0;
        for (int n = 0; n < 256; ++n) {
            float v = row[n];
            re += v * ct[idx];
            im -= v * st[idx];
            idx = (idx + t) & 255;
        }
        z[cy * 129 + t] = make_float2(re, im);
    }
}

__global__ __launch_bounds__(256) void dft_col_fwd2(
    const float2* __restrict__ z, unsigned short* __restrict__ fri16)
{
    int c  = blockIdx.x >> 8;
    int k1 = blockIdx.x & 255;
    __shared__ float ct[256], st[256];
    int t = threadIdx.x;
    float a = (2.0f * PI_F / 256.0f) * (float)t;
    ct[t] = cosf(a);
    st[t] = sinf(a);
    __syncthreads();
    if (t < 129) {
        float re = 0.f, im = 0.f;
        int idx = 0;
        for (int n1 = 0; n1 < 256; ++n1) {
            float2 zv = z[(c * 256 + n1) * 129 + t];
            float cw = ct[idx], sw = st[idx];
            re += zv.x * cw + zv.y * sw;
            im += zv.y * cw - zv.x * sw;
            idx = (idx + k1) & 255;
        }
        const float sc = 1.0f / 256.0f;
        size_t base = ((size_t)k1 * 132 + t) * 16;
        fri16[base + c]     = (unsigned short)bf16rne(re * sc);
        fri16[base + 8 + c] = (unsigned short)bf16rne(im * sc);
    }
}

__global__ __launch_bounds__(256) void dft_col_inv_kernel(
    const float* __restrict__ g, float2* __restrict__ z)
{
    int c  = blockIdx.x >> 8;
    int n1 = blockIdx.x & 255;
    __shared__ float ct[256], st[256];
    int t = threadIdx.x;
    float a = (2.0f * PI_F / 256.0f) * (float)t;
    ct[t] = cosf(a);
    st[t] = sinf(a);
    __syncthreads();
    if (t < 129) {
        float re = 0.f, im = 0.f;
        int idx = 0;
        for (int k1 = 0; k1 < 256; ++k1) {
            float gr = g[((size_t)c * 256 + k1) * 132 + t];
            float gi = g[((size_t)(4 + c) * 256 + k1) * 132 + t];
            float cw = ct[idx], sw = st[idx];
            re += gr * cw - gi * sw;
            im += gi * cw + gr * sw;
            idx = (idx + n1) & 255;
        }
        z[(c * 256 + n1) * 129 + t] = make_float2(re, im);
    }
}

__global__ __launch_bounds__(256) void irdft_row_add_kernel(
    const float2* __restrict__ z, float* __restrict__ corrected)
{
    int c  = blockIdx.x >> 8;
    int n1 = blockIdx.x & 255;
    __shared__ float2 yrow[129];
    __shared__ float ct[256], st[256];
    int t = threadIdx.x;
    if (t < 129) yrow[t] = z[(c * 256 + n1) * 129 + t];
    float a = (2.0f * PI_F / 256.0f) * (float)t;
    ct[t] = cosf(a);
    st[t] = sinf(a);
    __syncthreads();
    float acc = yrow[0].x + ((t & 1) ? -yrow[128].x : yrow[128].x);
    int idx = t;
    for (int k = 1; k <= 127; ++k) {
        float2 yv = yrow[k];
        acc += 2.0f * (yv.x * ct[idx] - yv.y * st[idx]);
        idx = (idx + t) & 255;
    }
    corrected[c * 65536 + n1 * 256 + t] += acc * (1.0f / 256.0f);
}

// ---------------------------------------------------------------------------
extern "C" void kernel_launch(void* const* d_in, const int* in_sizes, int n_in,
                              void* d_out, int out_size, void* d_ws, size_t ws_size,
                              hipStream_t stream)
{
    const float* raw = (const float*)d_in[0];
    const float* ab  = (const float*)d_in[1];
    const float* pw1 = (const float*)d_in[2];  const float* pb1 = (const float*)d_in[3];
    const float* pw2 = (const float*)d_in[4];  const float* pb2 = (const float*)d_in[5];
    const float* pw3 = (const float*)d_in[6];  const float* pb3 = (const float*)d_in[7];
    const float* fw1 = (const float*)d_in[8];  const float* fb1 = (const float*)d_in[9];
    const float* fw2 = (const float*)d_in[10]; const float* fb2 = (const float*)d_in[11];
    const float* fw3 = (const float*)d_in[12]; const float* fb3 = (const float*)d_in[13];
    const float* cw1 = (const float*)d_in[14]; const float* cb1 = (const float*)d_in[15];
    const float* cw2 = (const float*)d_in[16]; const float* cb2 = (const float*)d_in[17];
    const float* cw3 = (const float*)d_in[18]; const float* cb3 = (const float*)d_in[19];
    float* out = (float*)d_out;

    char* B = (char*)d_ws;
    unsigned short* h1b     = (unsigned short*)(B);              // 33,554,432 B (16 cb)
    unsigned short* h2b     = (unsigned short*)(B + 33554432);   // 16,777,216 B (8 cb)
    unsigned short* h1r     = (unsigned short*)(B + 33554432);   // alias (after psf)
    unsigned short* h2r     = (unsigned short*)(B + 41943040);
    float* corrected = (float*)(B + 50331648);                   // 1,048,576 B
    float2* zbuf     = (float2*)(B + 51380224);                  // 2,113,536 B
    unsigned short* fri16 = (unsigned short*)(B + 53493760);     // 2,162,688 B (2 cb, RS 132)
    unsigned short* g1b   = (unsigned short*)(B + 55656448);     // 4,325,376 B (4 cb)
    unsigned short* g2b   = (unsigned short*)(B + 59981824);     // 4,325,376 B
    float* gf        = (float*)(B + 64307200);                   // 1,081,344 B
    unsigned short* rw1  = (unsigned short*)(B + 65388544);      // 589,824 B
    unsigned short* rw2  = (unsigned short*)(B + 65978368);      // 589,824 B
    unsigned short* rw3  = (unsigned short*)(B + 66568192);      // 4 x 589,824 B
    unsigned short* rwf1 = (unsigned short*)(B + 68927488);      // 36,864 B
    unsigned short* rwf2 = (unsigned short*)(B + 68964352);      // 73,728 B
    unsigned short* rwf3 = (unsigned short*)(B + 69038080);      // 73,728 B
    unsigned short* wr2r = (unsigned short*)(B + 69111808);      // 20,480 B
    unsigned short* ab16 = (unsigned short*)(B + 69132288);      // 16,777,216 B

    dim3 blk(256);

    // weight repacks + input conversion
    repack_wA<<<512, blk, 0, stream>>>(pw1, rw1, 128, 4, 256, 8);
    repack_wA<<<512, blk, 0, stream>>>(pw2, rw2, 256, 8, 128, 4);
    for (int c = 0; c < 4; ++c)
        repack_wA<<<512, blk, 0, stream>>>(
            pw3 + (size_t)c * 225 * 128 * 9, rw3 + (size_t)c * 294912, 128, 4, 225, 8);
    repack_wA<<<64, blk, 0, stream>>>(fw1, rwf1, 8, 1, 64, 2);
    repack_wA<<<128, blk, 0, stream>>>(fw2, rwf2, 64, 2, 64, 2);
    repack_wA<<<128, blk, 0, stream>>>(fw3, rwf3, 64, 2, 8, 2);
    repack_wr2<<<40, blk, 0, stream>>>(cw2, wr2r);
    cvt_blocked<<<2048, blk, 0, stream>>>(ab, ab16, 128);

    // conv1: ab16(128) -> h1b(256), relu   [block = 256co x 64px, CT=2]
    conv_v9<true, 2, false><<<1024, blk, 0, stream>>>(
        ab16, (const short*)rw1, pb1, h1b, 4, 256, 8, 16, nullptr, nullptr);
    // conv2: h1b(256) -> h2b(128), relu    [block = 128co x 64px, CT=1]
    conv_v9<true, 1, false><<<1024, blk, 0, stream>>>(
        h1b, (const short*)rw2, pb2, h2b, 8, 128, 4, 8, nullptr, nullptr);
    // psf conv with FUSED softmax+patch epilogue, per image channel
    for (int c = 0; c < 4; ++c) {
        conv_v9<false, 2, true><<<1024, blk, 0, stream>>>(
            h2b, (const short*)(rw3 + (size_t)c * 294912), pb3 + c * 225, h1b,
            4, 225, 8, 15, raw + c * 65536, corrected + c * 65536);
    }
    // forward rfft2 (ortho)
    rdft_row_kernel<<<1024, blk, 0, stream>>>(corrected, zbuf);
    hipMemsetAsync(fri16, 0, 2162688, stream);
    dft_col_fwd2<<<1024, blk, 0, stream>>>(zbuf, fri16);
    // freq-domain convs (W=129, RS=132)
    conv_v4<true, true, 1><<<dim3(512, 1), blk, 0, stream>>>(
        fri16, (const short*)rwf1, fb1, g1b, 1, 64, 2, 129, 132, 4);
    conv_v4<true, true, 1><<<dim3(512, 1), blk, 0, stream>>>(
        g1b, (const short*)rwf2, fb2, g2b, 2, 64, 2, 129, 132, 4);
    conv_v4<false, false, 1><<<dim3(512, 1), blk, 0, stream>>>(
        g2b, (const short*)rwf3, fb3, gf, 2, 8, 2, 129, 132, 0);
    // inverse irfft2 (ortho), accumulate into corrected
    dft_col_inv_kernel<<<1024, blk, 0, stream>>>(gf, zbuf);
    irdft_row_add_kernel<<<1024, blk, 0, stream>>>(zbuf, corrected);
    // per-channel refinement, fused final clip
    refine1_kernel<<<1024, blk, 0, stream>>>(corrected, cw1, cb1, h1r);
    refine2_mfma<<<1024, blk, 0, stream>>>(h1r, wr2r, cb2, h2r);
    refine3_kernel<<<1024, blk, 0, stream>>>(h2r, cw3, cb3, raw, out);
}

// Round 18
// 458.229 us; speedup vs baseline: 2.3919x; 1.0302x over previous
//
#include <hip/hip_runtime.h>
#include <hip/hip_bf16.h>
#include <math.h>

#define PI_F 3.14159265358979323846f
// ci16 permutation (involution, swaps bits 2<->3): storage slot s holds channel PERM4(s)
#define PERM4(s) ((((s)&3)) + 8*(((s)>>2)&1) + 4*((s)>>3))

typedef short bfrag __attribute__((ext_vector_type(8)));   // 8 bf16 (4 VGPR)
typedef float f32x4 __attribute__((ext_vector_type(4)));
typedef float f32x16 __attribute__((ext_vector_type(16)));
typedef unsigned short us8 __attribute__((ext_vector_type(8)));

__device__ inline unsigned bf16rne(float x) {
    unsigned u = __builtin_bit_cast(unsigned, x);
    return (u + 0x7fffu + ((u >> 16) & 1u)) >> 16;
}
__device__ inline unsigned packbf2(float a, float b) {
    return bf16rne(a) | (bf16rne(b) << 16);
}
__device__ inline float bf2f(unsigned short u) {
    return __builtin_bit_cast(float, (unsigned)u << 16);
}
__device__ inline void glds16(const unsigned short* g, unsigned char* l) {
    __builtin_amdgcn_global_load_lds(
        (const __attribute__((address_space(1))) unsigned int*)g,
        (__attribute__((address_space(3))) unsigned int*)l, 16, 0, 0);
}

// ---------------------------------------------------------------------------
// conv_v9 (r15 known-good structure + r18 deltas): MFMA implicit-GEMM 3x3
// conv, pad 1, 32x32x16 bf16, W=256 ONLY. Double-buffered LDS + glds staging;
// cs0/dy0 A-frags loaded BEFORE the STAGE(c+1) issue. XCD swizzle: contiguous
// 32-row band per XCD. r18: interior blocks skip the LDS pre-zero (all glds
// lanes valid); s_setprio(1) around MFMA clusters (T5, cross-block phase
// diversity on each CU). SM=true (psf): fused softmax(225)+reflect-patch
// epilogue. DO NOT enlarge fragment arrays (r13/r16: spills past ~60 VGPR).
// IO: bf16 blocked [cb16][256 y][256 x][16 slots], slot s = ch PERM4(s).
// ---------------------------------------------------------------------------
template<bool RELU, int CT, bool SM>
__global__ __launch_bounds__(256, (CT == 2) ? 4 : 5) void conv_v9(
    const unsigned short* __restrict__ inb, const short* __restrict__ wp,
    const float* __restrict__ bias, unsigned short* __restrict__ ob,
    int C32, int Cout, int COT, int CBmax,
    const float* __restrict__ rawc, float* __restrict__ corr)
{
    int bid = blockIdx.x;
    bid = (bid & 7) * 128 + (bid >> 3);          // XCD swizzle (bijective, 1024 blocks)
    const int y  = bid >> 2;
    const int x0 = (bid & 3) << 6;
    const int t  = threadIdx.x;
    const int l  = t & 63;
    const int col = l & 31, kh = l >> 5;
    const int wv = t >> 6;
    const int ctg0 = wv * CT;

    __shared__ __align__(16) unsigned char sB[2][13824];   // 2 x (3 rows x 72 px x 64B)

    f32x16 acc[CT][2];
#pragma unroll
    for (int ct = 0; ct < CT; ++ct)
#pragma unroll
        for (int n = 0; n < 2; ++n)
#pragma unroll
            for (int i = 0; i < 16; ++i) acc[ct][n][i] = 0.f;

    int ba3[3];
#pragma unroll
    for (int dx = 0; dx < 3; ++dx) {
        int px = col + 3 + dx;
        ba3[dx] = px * 64 + ((kh ^ ((px >> 1) & 3)) << 4);   // cs -> ^32; n=1 -> +2048
    }

    // ---- staging lane constants: 4 glds issues cover 3 rows x 288 units ----
    int srcoff[4];
    bool vmask[4];
#pragma unroll
    for (int i = 0; i < 4; ++i) {
        int q = i * 256 + t;
        bool qv = q < 864;
        int row = q / 288;  if (row > 2) row = 2;
        int qr = q - row * 288;
        int px = qr >> 2, j = qr & 3;
        int u = j ^ ((px >> 1) & 3);
        int gx = x0 - 4 + px;
        int gy = y - 1 + row;
        vmask[i] = qv && ((unsigned)gx < 256u) && ((unsigned)gy < 256u);
        srcoff[i] = (((u >> 1) * 256 + gy) * 256 + gx) * 16 + (u & 1) * 8;
    }

    auto STAGE = [&](int c32, unsigned char* bufb) {
        const int coff = c32 * 2097152;          // 2 cb x 65536 px x 16 ushorts
#pragma unroll
        for (int i = 0; i < 4; ++i)
            if (vmask[i])
                glds16(inb + (srcoff[i] + coff), bufb + (i << 12) + (wv << 10));
    };

    // pre-zero both buffers only when some glds lanes are masked off
    // (boundary blocks); interior blocks have every cell written each chunk.
    if (x0 == 0 || x0 == 192 || y == 0 || y == 255) {
        for (int i = t; i < 1728; i += 256)
            *(uint4*)(&sB[0][0] + i * 16) = make_uint4(0, 0, 0, 0);
        __syncthreads();
    }

    const bfrag* wA = (const bfrag*)wp;
    const int tstr = C32 * 2 * COT * 64;

    auto LOAD_AF = [&](bfrag (&af)[3][CT], int abase, int dy) {
#pragma unroll
        for (int dx = 0; dx < 3; ++dx)
#pragma unroll
            for (int ct = 0; ct < CT; ++ct)
                af[dx][ct] = wA[abase + ct * 64 + (size_t)(dy * 3 + dx) * tstr];
    };
    auto MFMA_DY = [&](const bfrag (&af)[3][CT], const unsigned char* rp, int csx) {
        __builtin_amdgcn_s_setprio(1);
#pragma unroll
        for (int dx = 0; dx < 3; ++dx) {
            const int ba = ba3[dx] ^ csx;
            bfrag b0 = *(const bfrag*)(rp + ba);
            bfrag b1 = *(const bfrag*)(rp + ba + 2048);
#pragma unroll
            for (int ct = 0; ct < CT; ++ct) {
                acc[ct][0] = __builtin_amdgcn_mfma_f32_32x32x16_bf16(af[dx][ct], b0, acc[ct][0], 0, 0, 0);
                acc[ct][1] = __builtin_amdgcn_mfma_f32_32x32x16_bf16(af[dx][ct], b1, acc[ct][1], 0, 0, 0);
            }
        }
        __builtin_amdgcn_s_setprio(0);
    };

    STAGE(0, sB[0]);
    __syncthreads();
    for (int c32 = 0; c32 < C32; ++c32) {
        const unsigned char* bufp = sB[c32 & 1];
        const int ab0 = (c32 * 2 * COT + ctg0) * 64 + l;
        const int ab1 = ((c32 * 2 + 1) * COT + ctg0) * 64 + l;
        bfrag af0[3][CT];
        LOAD_AF(af0, ab0, 0);                              // BEFORE stage issue
        if (c32 + 1 < C32) STAGE(c32 + 1, sB[(c32 + 1) & 1]);
        MFMA_DY(af0, bufp, 0);                             // cs=0, dy=0
#pragma unroll
        for (int dy = 1; dy < 3; ++dy) {                   // cs=0, dy=1..2
            bfrag af[3][CT];
            LOAD_AF(af, ab0, dy);
            MFMA_DY(af, bufp + dy * 4608, 0);
        }
#pragma unroll
        for (int dy = 0; dy < 3; ++dy) {                   // cs=1, dy=0..2
            bfrag af[3][CT];
            LOAD_AF(af, ab1, dy);
            MFMA_DY(af, bufp + dy * 4608, 32);
        }
        __syncthreads();   // drains next-stage glds + this chunk's LDS reads
    }

    if (SM) {
        // --------- fused softmax(225) + reflect-patch epilogue ---------
        // stage raw window (15 x 80, reflect applied) + bias + tap offsets
        float* sRaw  = (float*)&sB[0][0];        // 1200 floats
        float* sBias = (float*)&sB[0][4800];     // 225 floats
        int*   sOff  = (int*)&sB[0][5700];       // 225 ints: ty*80+tx = t + 65*(t/15)
        float* red   = (float*)&sB[1][0];        // 64 px x 4 g x 3 floats
        for (int i = t; i < 1200; i += 256) {
            int r = i / 80, xx = i - r * 80;
            int gy = y + r - 7;
            gy = gy < 0 ? -gy : (gy > 255 ? 510 - gy : gy);
            int gx = x0 + xx - 7;
            gx = gx < 0 ? -gx : (gx > 255 ? 510 - gx : gx);
            sRaw[i] = rawc[gy * 256 + gx];
        }
        if (t < 225) {
            sBias[t] = bias[t];
            sOff[t]  = t + 65 * (t / 15);
        }
        __syncthreads();

        float pm[2], ps[2], pa[2];
#pragma unroll
        for (int n = 0; n < 2; ++n) {
            float m = -1e30f, s = 0.f, a = 0.f;
            const int xb = col + n * 32;         // local x (gx_local = xb + tx)
#pragma unroll
            for (int ct = 0; ct < CT; ++ct) {
                const f32x16 A = acc[ct][n];
#pragma unroll
                for (int rh = 0; rh < 2; ++rh) {
                    int cb = (ctg0 + ct) * 2 + rh;
#pragma unroll
                    for (int j = 0; j < 8; ++j) {
                        int co = cb * 16 + (j & 3) + 8 * (j >> 2) + 4 * kh;
                        if (co < 225) {
                            float lv = A[rh * 8 + j] + sBias[co];
                            float pv = sRaw[sOff[co] + xb];
                            if (lv > m + 4.f) { float rs = __expf(m - lv); s *= rs; a *= rs; m = lv; }
                            float e = __expf(lv - m);
                            s += e; a += e * pv;
                        }
                    }
                }
            }
            // in-wave kh merge (lanes l <-> l^32 hold same px, other kh half)
            float mo = __shfl_xor(m, 32), so = __shfl_xor(s, 32), ao = __shfl_xor(a, 32);
            float M = fmaxf(m, mo);
            float e0 = __expf(m - M), e1 = __expf(mo - M);
            pm[n] = M;
            ps[n] = s * e0 + so * e1;
            pa[n] = a * e0 + ao * e1;
        }
        // cross-wave merge: 4 groups (wv), px = col + n*32
        if (kh == 0) {
#pragma unroll
            for (int n = 0; n < 2; ++n) {
                int px = col + n * 32;
                red[(px * 4 + wv) * 3 + 0] = pm[n];
                red[(px * 4 + wv) * 3 + 1] = ps[n];
                red[(px * 4 + wv) * 3 + 2] = pa[n];
            }
        }
        __syncthreads();
        if (t < 64) {
            float m = red[(t * 4) * 3], s = red[(t * 4) * 3 + 1], a = red[(t * 4) * 3 + 2];
#pragma unroll
            for (int gg = 1; gg < 4; ++gg) {
                float mg = red[(t * 4 + gg) * 3], sg = red[(t * 4 + gg) * 3 + 1], ag = red[(t * 4 + gg) * 3 + 2];
                float M = fmaxf(m, mg);
                float s0 = __expf(m - M), s1 = __expf(mg - M);
                s = s * s0 + sg * s1;
                a = a * s0 + ag * s1;
                m = M;
            }
            corr[y * 256 + x0 + t] = a / s;
        }
    } else {
        // epilogue: C/D col = l&31 (px), row = (reg&3)+8*(reg>>2)+4*kh
#pragma unroll
        for (int ct = 0; ct < CT; ++ct) {
            const int ctg = ctg0 + ct;
#pragma unroll
            for (int n = 0; n < 2; ++n) {
                const int xx = x0 + col + n * 32;
                const f32x16 A = acc[ct][n];
#pragma unroll
                for (int rh = 0; rh < 2; ++rh) {
                    int cb = ctg * 2 + rh;
                    if (cb >= CBmax) continue;
                    unsigned wd[4];
#pragma unroll
                    for (int jp = 0; jp < 4; ++jp) {
                        float vv[2];
#pragma unroll
                        for (int e = 0; e < 2; ++e) {
                            int j = jp * 2 + e;
                            int co = cb * 16 + (j & 3) + 8 * (j >> 2) + 4 * kh;
                            float bv = (co < Cout) ? bias[co] : 0.f;
                            float v = A[rh * 8 + j] + bv;
                            if (RELU) v = fmaxf(v, 0.f);
                            vv[e] = v;
                        }
                        wd[jp] = packbf2(vv[0], vv[1]);
                    }
                    *(uint4*)(ob + ((((size_t)cb << 8) + y) * 256 + xx) * 16 + (kh << 3)) =
                        make_uint4(wd[0], wd[1], wd[2], wd[3]);
                }
            }
        }
    }
}

// ---------------------------------------------------------------------------
// conv_v4 (reg-staged, generic W/RS) — kept for the freq-domain convs.
// ---------------------------------------------------------------------------
template<bool RELU, bool OUT_BF16, int CT>
__global__ __launch_bounds__(256, 3) void conv_v4(
    const unsigned short* __restrict__ inb, const short* __restrict__ wp,
    const float* __restrict__ bias, void* __restrict__ outv,
    int C32, int Cout, int COT, int W, int RSg, int CBmax)
{
    const int tilesx = (W + 127) >> 7;
    const int y  = blockIdx.x / tilesx;
    const int x0 = (blockIdx.x % tilesx) << 7;
    const int t  = threadIdx.x;
    const int l  = t & 63;
    const int col = l & 31, kh = l >> 5;
    const int wv = t >> 6;
    const int wct = wv & 1, wpt = wv >> 1;
    const int ctg0 = (blockIdx.y * 2 + wct) * CT;

    __shared__ __align__(16) unsigned char sB[26112];

    f32x16 acc[CT][2];
#pragma unroll
    for (int ct = 0; ct < CT; ++ct)
#pragma unroll
        for (int n = 0; n < 2; ++n)
#pragma unroll
            for (int i = 0; i < 16; ++i) acc[ct][n][i] = 0.f;

    int ba3[3];
#pragma unroll
    for (int dx = 0; dx < 3; ++dx) {
        int px = wpt * 64 + col + 3 + dx;
        ba3[dx] = px * 64 + ((kh ^ ((px >> 1) & 3)) << 4);
    }

    const int pxm = (t & 127) + 4, thalf = t >> 7;
    const int gxm = x0 + (t & 127);
    const bool gxok = gxm < W;
    const int offm_e = pxm * 64 + ((thalf ^ ((pxm >> 1) & 3)) << 4);
    const int hr = t >> 5, hj = t & 31, hg = hj >> 3, hp = hj & 7;
    const int hslot = hp + ((hp >> 2) << 7);
    const int hgx = x0 - 4 + hslot;
    const int hoff = hr * 8704 + hslot * 64 + ((hg ^ ((hslot >> 1) & 3)) << 4);
    const int hgy = y + hr - 1;
    const bool hok = (t < 96) && ((unsigned)hgy < 256u) && ((unsigned)hgx < (unsigned)W);

    auto STAGE = [&](int c32) {
        const int cb0 = c32 << 1;
#pragma unroll
        for (int k = 0; k < 6; ++k) {
            const int r = k >> 1;
            const int cb = cb0 + (k & 1);
            const int gy = y + r - 1;
            uint4 v = make_uint4(0, 0, 0, 0);
            if (gxok && (unsigned)gy < 256u)
                v = *(const uint4*)(inb + ((((size_t)cb << 8) + gy) * RSg + gxm) * 16 + (thalf << 3));
            *(uint4*)(sB + r * 8704 + (offm_e ^ ((k & 1) << 5))) = v;
        }
        if (t < 96) {
            uint4 v = make_uint4(0, 0, 0, 0);
            if (hok) v = *(const uint4*)(inb + ((((size_t)(cb0 + (hg >> 1)) << 8) + hgy) * RSg + hgx) * 16 + ((hg & 1) << 3));
            *(uint4*)(sB + hoff) = v;
        }
    };

    const bfrag* wA = (const bfrag*)wp;
    const int tstr = C32 * 2 * COT * 64;

    STAGE(0);
    __syncthreads();
    for (int c32 = 0; c32 < C32; ++c32) {
#pragma unroll 1
        for (int cs = 0; cs < 2; ++cs) {
            const int abase = ((c32 * 2 + cs) * COT + ctg0) * 64 + l;
            const int csx = cs << 5;
#pragma unroll
            for (int dy = 0; dy < 3; ++dy) {
                bfrag af[3][CT];
#pragma unroll
                for (int dx = 0; dx < 3; ++dx)
#pragma unroll
                    for (int ct = 0; ct < CT; ++ct)
                        af[dx][ct] = wA[abase + ct * 64 + (size_t)(dy * 3 + dx) * tstr];
                const unsigned char* rp = sB + dy * 8704;
#pragma unroll
                for (int dx = 0; dx < 3; ++dx) {
                    const int ba = ba3[dx] ^ csx;
                    bfrag b0 = *(const bfrag*)(rp + ba);
                    bfrag b1 = *(const bfrag*)(rp + ba + 2048);
#pragma unroll
                    for (int ct = 0; ct < CT; ++ct) {
                        acc[ct][0] = __builtin_amdgcn_mfma_f32_32x32x16_bf16(af[dx][ct], b0, acc[ct][0], 0, 0, 0);
                        acc[ct][1] = __builtin_amdgcn_mfma_f32_32x32x16_bf16(af[dx][ct], b1, acc[ct][1], 0, 0, 0);
                    }
                }
            }
        }
        __syncthreads();
        if (c32 + 1 < C32) { STAGE(c32 + 1); __syncthreads(); }
    }

    const int xBase = x0 + wpt * 64 + col;
#pragma unroll
    for (int ct = 0; ct < CT; ++ct) {
        const int ctg = ctg0 + ct;
#pragma unroll
        for (int n = 0; n < 2; ++n) {
            int xx = xBase + n * 32;
            if (xx >= W) continue;
            const f32x16 A = acc[ct][n];
            if (OUT_BF16) {
                unsigned short* ob = (unsigned short*)outv;
#pragma unroll
                for (int rh = 0; rh < 2; ++rh) {
                    int cb = ctg * 2 + rh;
                    if (cb >= CBmax) continue;
                    unsigned wd[4];
#pragma unroll
                    for (int jp = 0; jp < 4; ++jp) {
                        float vv[2];
#pragma unroll
                        for (int e = 0; e < 2; ++e) {
                            int j = jp * 2 + e;
                            int co = cb * 16 + (j & 3) + 8 * (j >> 2) + 4 * kh;
                            float bv = (co < Cout) ? bias[co] : 0.f;
                            float v = A[rh * 8 + j] + bv;
                            if (RELU) v = fmaxf(v, 0.f);
                            vv[e] = v;
                        }
                        wd[jp] = packbf2(vv[0], vv[1]);
                    }
                    *(uint4*)(ob + ((((size_t)cb << 8) + y) * RSg + xx) * 16 + (kh << 3)) =
                        make_uint4(wd[0], wd[1], wd[2], wd[3]);
                }
            } else {
                float* of = (float*)outv;
#pragma unroll
                for (int reg = 0; reg < 16; ++reg) {
                    int co = ctg * 32 + (reg & 3) + 8 * (reg >> 2) + 4 * kh;
                    if (co < Cout) {
                        float v = A[reg] + bias[co];
                        if (RELU) v = fmaxf(v, 0.f);
                        of[(((size_t)co << 8) + y) * RSg + xx] = v;
                    }
                }
            }
        }
    }
}

// ---------------------------------------------------------------------------
// Merged weight repack: 9 repack_wA jobs in ONE launch (saves 8 launch gaps).
// Same per-element layout as repack_wA.
// ---------------------------------------------------------------------------
struct RepackJob { const float* w; unsigned short* o; int Cin, C32, Cout, COT, blk0, nblk; };
struct RepackJobs { RepackJob j[9]; };

__global__ __launch_bounds__(256) void repack_multi(RepackJobs J)
{
    int b = blockIdx.x;
    int ji = 0;
#pragma unroll
    for (int k = 1; k < 9; ++k) if (b >= J.j[k].blk0) ji = k;
    const RepackJob jb = J.j[ji];
    int rb = b - jb.blk0;
    int total = 9 * jb.C32 * 2 * jb.COT * 512;
    for (int i = rb * 256 + threadIdx.x; i < total; i += jb.nblk * 256) {
        int j = i & 7;
        int l = (i >> 3) & 63;
        int rest = i >> 9;
        int ct = rest % jb.COT; rest /= jb.COT;
        int cs = rest & 1; rest >>= 1;
        int c32 = rest % jb.C32;
        int tap = rest / jb.C32;
        int co = ct * 32 + (l & 31);
        int s = ((l >> 5) << 3) + j;
        int ci = c32 * 32 + cs * 16 + PERM4(s);
        float v = (co < jb.Cout && ci < jb.Cin) ? jb.w[((size_t)co * jb.Cin + ci) * 9 + tap] : 0.f;
        jb.o[i] = (unsigned short)bf16rne(v);
    }
}

// fp32 NCHW [C][256][256] -> bf16 blocked [CB][y][x][16] with PERM slots
__global__ __launch_bounds__(256) void cvt_blocked(
    const float* __restrict__ src, unsigned short* __restrict__ dst, int C)
{
    int cb = blockIdx.x >> 8;
    int y  = blockIdx.x & 255;
    int x  = threadIdx.x;
    unsigned wd[8];
#pragma unroll
    for (int q = 0; q < 8; ++q) {
        float v[2];
#pragma unroll
        for (int e = 0; e < 2; ++e) {
            int s = q * 2 + e;
            int ci = (cb << 4) + PERM4(s);
            v[e] = (ci < C) ? src[((size_t)ci * 256 + y) * 256 + x] : 0.f;
        }
        wd[q] = packbf2(v[0], v[1]);
    }
    unsigned short* dp = dst + (((size_t)cb << 16) + (y << 8) + x) * 16;
    *(uint4*)dp = make_uint4(wd[0], wd[1], wd[2], wd[3]);
    *(uint4*)(dp + 8) = make_uint4(wd[4], wd[5], wd[6], wd[7]);
}

// ---------------------------------------------------------------------------
// Refinement
// ---------------------------------------------------------------------------
__global__ __launch_bounds__(256) void repack_wr2(
    const float* __restrict__ cw2, unsigned short* __restrict__ o)
{
    int i = blockIdx.x * 256 + threadIdx.x;
    if (i >= 10240) return;
    int k = i & 31, rest = i >> 5;
    int co = rest & 15;
    int kt = (rest >> 4) % 5;
    int ch = rest / 80;
    int tap = 2 * kt + (k >= 16 ? 1 : 0), ci = k & 15;
    float v = 0.f;
    if (tap < 9) v = cw2[(((size_t)ch * 16 + co) * 16 + ci) * 9 + tap];
    o[i] = (unsigned short)bf16rne(v);
}

__global__ __launch_bounds__(256) void refine1_kernel(
    const float* __restrict__ corrected, const float* __restrict__ cw1,
    const float* __restrict__ cb1, unsigned short* __restrict__ h1b)
{
    const int c = blockIdx.x >> 8;
    const int y = blockIdx.x & 255;
    const int t = threadIdx.x;
    __shared__ float sIn[3][258];
    __shared__ float sW[144];
    __shared__ float sBv[16];
    if (t < 144) sW[t] = cw1[c * 144 + t];
    if (t >= 144 && t < 160) sBv[t - 144] = cb1[c * 16 + (t - 144)];
    for (int i = t; i < 774; i += 256) {
        int r = i / 258, xx = i % 258;
        int gy = y + r - 1, gx = xx - 1;
        sIn[r][xx] = ((unsigned)gy < 256u && (unsigned)gx < 256u)
                   ? corrected[((size_t)c * 256 + gy) * 256 + gx] : 0.f;
    }
    __syncthreads();
    float a[9];
#pragma unroll
    for (int dy = 0; dy < 3; ++dy)
#pragma unroll
        for (int dx = 0; dx < 3; ++dx) a[dy * 3 + dx] = sIn[dy][t + dx];
    unsigned short ov[16];
#pragma unroll
    for (int co = 0; co < 16; ++co) {
        float acc = sBv[co];
#pragma unroll
        for (int tap = 0; tap < 9; ++tap) acc += a[tap] * sW[co * 9 + tap];
        acc = fmaxf(acc, 0.f);
        ov[co] = (unsigned short)bf16rne(acc);
    }
    unsigned short* op = h1b + ((((size_t)c * 256 + y) * 256 + t) << 4);
    *(uint4*)op = *(uint4*)ov;
    *(uint4*)(op + 8) = *(uint4*)(ov + 8);
}

__global__ __launch_bounds__(256) void refine2_mfma(
    const unsigned short* __restrict__ h1b, const unsigned short* __restrict__ wr2,
    const float* __restrict__ cb2, unsigned short* __restrict__ h2b)
{
    const int c = blockIdx.x >> 8;
    const int y = blockIdx.x & 255;
    const int t = threadIdx.x;
    const int l15 = t & 15, lg = (t >> 4) & 3, wv = t >> 6;

    __shared__ __align__(16) unsigned char sA[3 * 258 * 32];

    for (int i = t; i < 1548; i += 256) {
        int r = i / 516, u = i % 516;
        int px = u >> 1, half = u & 1;
        int gy = y + r - 1, gx = px - 1;
        uint4 v = make_uint4(0, 0, 0, 0);
        if ((unsigned)gy < 256u && (unsigned)gx < 256u)
            v = *(const uint4*)(h1b + ((((size_t)c * 256 + gy) * 256 + gx) << 4) + (half << 3));
        *(uint4*)(sA + r * 8256 + px * 32 + ((half ^ ((px >> 2) & 1)) << 4)) = v;
    }
    __syncthreads();

    f32x4 acc[4];
#pragma unroll
    for (int n = 0; n < 4; ++n) acc[n] = (f32x4){0.f, 0.f, 0.f, 0.f};
    const bfrag* wf = (const bfrag*)(wr2 + (size_t)c * 2560);
    const int strip = wv * 64;
#pragma unroll
    for (int kt = 0; kt < 5; ++kt) {
        bfrag a = wf[(kt * 16 + l15) * 4 + lg];
        int tap1 = 2 * kt + 1; if (tap1 > 8) tap1 = 8;
        int tap = (lg < 2) ? (2 * kt) : tap1;
        int dy = tap / 3, dx = tap % 3;
#pragma unroll
        for (int n = 0; n < 4; ++n) {
            int pxs = strip + n * 16 + l15 + dx;
            bfrag b = *(const bfrag*)(sA + dy * 8256 + pxs * 32 +
                                      (((lg & 1) ^ ((pxs >> 2) & 1)) << 4));
            acc[n] = __builtin_amdgcn_mfma_f32_16x16x32_bf16(a, b, acc[n], 0, 0, 0);
        }
    }

#pragma unroll
    for (int n = 0; n < 4; ++n) {
        int px = strip + n * 16 + l15;
        unsigned short ov[4];
#pragma unroll
        for (int r = 0; r < 4; ++r) {
            int co = lg * 4 + r;
            float v = acc[n][r] + cb2[c * 16 + co];
            v = fmaxf(v, 0.f);
            ov[r] = (unsigned short)bf16rne(v);
        }
        *(ushort4*)(h2b + ((((size_t)c * 256 + y) * 256 + px) << 4) + lg * 4) = *(ushort4*)ov;
    }
}

__global__ __launch_bounds__(256) void refine3_kernel(
    const unsigned short* __restrict__ h2b, const float* __restrict__ cw3,
    const float* __restrict__ cb3, const float* __restrict__ raw,
    float* __restrict__ out)
{
    const int c = blockIdx.x >> 8;
    const int y = blockIdx.x & 255;
    const int t = threadIdx.x;
    __shared__ __align__(16) unsigned char sA[3 * 258 * 32];
    __shared__ float sW[144];
    if (t < 144) sW[t] = cw3[c * 144 + t];
    for (int i = t; i < 1548; i += 256) {
        int r = i / 516, u = i % 516;
        int px = u >> 1, half = u & 1;
        int gy = y + r - 1, gx = px - 1;
        uint4 v = make_uint4(0, 0, 0, 0);
        if ((unsigned)gy < 256u && (unsigned)gx < 256u)
            v = *(const uint4*)(h2b + ((((size_t)c * 256 + gy) * 256 + gx) << 4) + (half << 3));
        *(uint4*)(sA + r * 8256 + px * 32 + ((half ^ ((px >> 2) & 1)) << 4)) = v;
    }
    __syncthreads();
    float acc = cb3[c];
#pragma unroll
    for (int tap = 0; tap < 9; ++tap) {
        int dy = tap / 3, dx = tap % 3;
        int px = t + dx;
        const unsigned char* p = sA + dy * 8256 + px * 32;
        int sw = ((px >> 2) & 1) << 4;
        us8 h0 = *(const us8*)(p + (sw ^ 0));
        us8 h1 = *(const us8*)(p + (sw ^ 16));
#pragma unroll
        for (int j = 0; j < 8; ++j) acc += bf2f(h0[j]) * sW[j * 9 + tap];
#pragma unroll
        for (int j = 0; j < 8; ++j) acc += bf2f(h1[j]) * sW[(8 + j) * 9 + tap];
    }
    size_t idx = ((size_t)c * 256 + y) * 256 + t;
    float v = raw[idx] + acc;
    out[idx] = fminf(fmaxf(v, 0.f), 1.f);
}

// ---------------------------------------------------------------------------
// DFT kernels
// ---------------------------------------------------------------------------
__global__ __launch_bounds__(256) void rdft_row_kernel(
    const float* __restrict__ x, float2* __restrict__ z)
{
    int cy = blockIdx.x;
    __shared__ float row[256];
    __shared__ float ct[256], st[256];
    int t = threadIdx.x;
    row[t] = x[cy * 256 + t];
    float a = (2.0f * PI_F / 256.0f) * (float)t;
    ct[t] = cosf(a);
    st[t] = sinf(a);
    __syncthreads();
    if (t < 129) {
        float re = 0.f, im = 0.f;
        int idx = 0;
        for (int n = 0; n < 256; ++n) {
            float v = row[n];
            re += v * ct[idx];
            im -= v * st[idx];
            idx = (idx + t) & 255;
        }
        z[cy * 129 + t] = make_float2(re, im);
    }
}

__global__ __launch_bounds__(256) void dft_col_fwd2(
    const float2* __restrict__ z, unsigned short* __restrict__ fri16)
{
    int c  = blockIdx.x >> 8;
    int k1 = blockIdx.x & 255;
    __shared__ float ct[256], st[256];
    int t = threadIdx.x;
    float a = (2.0f * PI_F / 256.0f) * (float)t;
    ct[t] = cosf(a);
    st[t] = sinf(a);
    __syncthreads();
    if (t < 129) {
        float re = 0.f, im = 0.f;
        int idx = 0;
        for (int n1 = 0; n1 < 256; ++n1) {
            float2 zv = z[(c * 256 + n1) * 129 + t];
            float cw = ct[idx], sw = st[idx];
            re += zv.x * cw + zv.y * sw;
            im += zv.y * cw - zv.x * sw;
            idx = (idx + k1) & 255;
        }
        const float sc = 1.0f / 256.0f;
        size_t base = ((size_t)k1 * 132 + t) * 16;
        fri16[base + c]     = (unsigned short)bf16rne(re * sc);
        fri16[base + 8 + c] = (unsigned short)bf16rne(im * sc);
    }
}

__global__ __launch_bounds__(256) void dft_col_inv_kernel(
    const float* __restrict__ g, float2* __restrict__ z)
{
    int c  = blockIdx.x >> 8;
    int n1 = blockIdx.x & 255;
    __shared__ float ct[256], st[256];
    int t = threadIdx.x;
    float a = (2.0f * PI_F / 256.0f) * (float)t;
    ct[t] = cosf(a);
    st[t] = sinf(a);
    __syncthreads();
    if (t < 129) {
        float re = 0.f, im = 0.f;
        int idx = 0;
        for (int k1 = 0; k1 < 256; ++k1) {
            float gr = g[((size_t)c * 256 + k1) * 132 + t];
            float gi = g[((size_t)(4 + c) * 256 + k1) * 132 + t];
            float cw = ct[idx], sw = st[idx];
            re += gr * cw - gi * sw;
            im += gi * cw + gr * sw;
            idx = (idx + n1) & 255;
        }
        z[(c * 256 + n1) * 129 + t] = make_float2(re, im);
    }
}

__global__ __launch_bounds__(256) void irdft_row_add_kernel(
    const float2* __restrict__ z, float* __restrict__ corrected)
{
    int c  = blockIdx.x >> 8;
    int n1 = blockIdx.x & 255;
    __shared__ float2 yrow[129];
    __shared__ float ct[256], st[256];
    int t = threadIdx.x;
    if (t < 129) yrow[t] = z[(c * 256 + n1) * 129 + t];
    float a = (2.0f * PI_F / 256.0f) * (float)t;
    ct[t] = cosf(a);
    st[t] = sinf(a);
    __syncthreads();
    float acc = yrow[0].x + ((t & 1) ? -yrow[128].x : yrow[128].x);
    int idx = t;
    for (int k = 1; k <= 127; ++k) {
        float2 yv = yrow[k];
        acc += 2.0f * (yv.x * ct[idx] - yv.y * st[idx]);
        idx = (idx + t) & 255;
    }
    corrected[c * 65536 + n1 * 256 + t] += acc * (1.0f / 256.0f);
}

// ---------------------------------------------------------------------------
extern "C" void kernel_launch(void* const* d_in, const int* in_sizes, int n_in,
                              void* d_out, int out_size, void* d_ws, size_t ws_size,
                              hipStream_t stream)
{
    const float* raw = (const float*)d_in[0];
    const float* ab  = (const float*)d_in[1];
    const float* pw1 = (const float*)d_in[2];  const float* pb1 = (const float*)d_in[3];
    const float* pw2 = (const float*)d_in[4];  const float* pb2 = (const float*)d_in[5];
    const float* pw3 = (const float*)d_in[6];  const float* pb3 = (const float*)d_in[7];
    const float* fw1 = (const float*)d_in[8];  const float* fb1 = (const float*)d_in[9];
    const float* fw2 = (const float*)d_in[10]; const float* fb2 = (const float*)d_in[11];
    const float* fw3 = (const float*)d_in[12]; const float* fb3 = (const float*)d_in[13];
    const float* cw1 = (const float*)d_in[14]; const float* cb1 = (const float*)d_in[15];
    const float* cw2 = (const float*)d_in[16]; const float* cb2 = (const float*)d_in[17];
    const float* cw3 = (const float*)d_in[18]; const float* cb3 = (const float*)d_in[19];
    float* out = (float*)d_out;

    char* B = (char*)d_ws;
    unsigned short* h1b     = (unsigned short*)(B);              // 33,554,432 B (16 cb)
    unsigned short* h2b     = (unsigned short*)(B + 33554432);   // 16,777,216 B (8 cb)
    unsigned short* h1r     = (unsigned short*)(B + 33554432);   // alias (after psf)
    unsigned short* h2r     = (unsigned short*)(B + 41943040);
    float* corrected = (float*)(B + 50331648);                   // 1,048,576 B
    float2* zbuf     = (float2*)(B + 51380224);                  // 2,113,536 B
    unsigned short* fri16 = (unsigned short*)(B + 53493760);     // 2,162,688 B (2 cb, RS 132)
    unsigned short* g1b   = (unsigned short*)(B + 55656448);     // 4,325,376 B (4 cb)
    unsigned short* g2b   = (unsigned short*)(B + 59981824);     // 4,325,376 B
    float* gf        = (float*)(B + 64307200);                   // 1,081,344 B
    unsigned short* rw1  = (unsigned short*)(B + 65388544);      // 589,824 B
    unsigned short* rw2  = (unsigned short*)(B + 65978368);      // 589,824 B
    unsigned short* rw3  = (unsigned short*)(B + 66568192);      // 4 x 589,824 B
    unsigned short* rwf1 = (unsigned short*)(B + 68927488);      // 36,864 B
    unsigned short* rwf2 = (unsigned short*)(B + 68964352);      // 73,728 B
    unsigned short* rwf3 = (unsigned short*)(B + 69038080);      // 73,728 B
    unsigned short* wr2r = (unsigned short*)(B + 69111808);      // 20,480 B
    unsigned short* ab16 = (unsigned short*)(B + 69132288);      // 16,777,216 B

    dim3 blk(256);

    // merged weight repacks (one launch) + remaining converts
    RepackJobs J;
    J.j[0] = { pw1,                    rw1,                128, 4, 256, 8,    0, 512 };
    J.j[1] = { pw2,                    rw2,                256, 8, 128, 4,  512, 512 };
    J.j[2] = { pw3 + 0 * 259200,       rw3 + 0 * 294912,   128, 4, 225, 8, 1024, 512 };
    J.j[3] = { pw3 + 1 * 259200,       rw3 + 1 * 294912,   128, 4, 225, 8, 1536, 512 };
    J.j[4] = { pw3 + 2 * 259200,       rw3 + 2 * 294912,   128, 4, 225, 8, 2048, 512 };
    J.j[5] = { pw3 + 3 * 259200,       rw3 + 3 * 294912,   128, 4, 225, 8, 2560, 512 };
    J.j[6] = { fw1,                    rwf1,                 8, 1,  64, 2, 3072,  64 };
    J.j[7] = { fw2,                    rwf2,                64, 2,  64, 2, 3136, 128 };
    J.j[8] = { fw3,                    rwf3,                64, 2,   8, 2, 3264, 128 };
    repack_multi<<<3392, blk, 0, stream>>>(J);
    repack_wr2<<<40, blk, 0, stream>>>(cw2, wr2r);
    cvt_blocked<<<2048, blk, 0, stream>>>(ab, ab16, 128);

    // conv1: ab16(128) -> h1b(256), relu   [block = 256co x 64px, CT=2]
    conv_v9<true, 2, false><<<1024, blk, 0, stream>>>(
        ab16, (const short*)rw1, pb1, h1b, 4, 256, 8, 16, nullptr, nullptr);
    // conv2: h1b(256) -> h2b(128), relu    [block = 128co x 64px, CT=1]
    conv_v9<true, 1, false><<<1024, blk, 0, stream>>>(
        h1b, (const short*)rw2, pb2, h2b, 8, 128, 4, 8, nullptr, nullptr);
    // psf conv with FUSED softmax+patch epilogue, per image channel
    for (int c = 0; c < 4; ++c) {
        conv_v9<false, 2, true><<<1024, blk, 0, stream>>>(
            h2b, (const short*)(rw3 + (size_t)c * 294912), pb3 + c * 225, h1b,
            4, 225, 8, 15, raw + c * 65536, corrected + c * 65536);
    }
    // forward rfft2 (ortho)
    rdft_row_kernel<<<1024, blk, 0, stream>>>(corrected, zbuf);
    hipMemsetAsync(fri16, 0, 2162688, stream);
    dft_col_fwd2<<<1024, blk, 0, stream>>>(zbuf, fri16);
    // freq-domain convs (W=129, RS=132)
    conv_v4<true, true, 1><<<dim3(512, 1), blk, 0, stream>>>(
        fri16, (const short*)rwf1, fb1, g1b, 1, 64, 2, 129, 132, 4);
    conv_v4<true, true, 1><<<dim3(512, 1), blk, 0, stream>>>(
        g1b, (const short*)rwf2, fb2, g2b, 2, 64, 2, 129, 132, 4);
    conv_v4<false, false, 1><<<dim3(512, 1), blk, 0, stream>>>(
        g2b, (const short*)rwf3, fb3, gf, 2, 8, 2, 129, 132, 0);
    // inverse irfft2 (ortho), accumulate into corrected
    dft_col_inv_kernel<<<1024, blk, 0, stream>>>(gf, zbuf);
    irdft_row_add_kernel<<<1024, blk, 0, stream>>>(zbuf, corrected);
    // per-channel refinement, fused final clip
    refine1_kernel<<<1024, blk, 0, stream>>>(corrected, cw1, cb1, h1r);
    refine2_mfma<<<1024, blk, 0, stream>>>(h1r, wr2r, cb2, h2r);
    refine3_kernel<<<1024, blk, 0, stream>>>(h2r, cw3, cb3, raw, out);
}

// Round 19
// 432.011 us; speedup vs baseline: 2.5371x; 1.0607x over previous
//
#include <hip/hip_runtime.h>
#include <hip/hip_bf16.h>
#include <math.h>

#define PI_F 3.14159265358979323846f
// ci16 permutation (involution, swaps bits 2<->3): storage slot s holds channel PERM4(s)
#define PERM4(s) ((((s)&3)) + 8*(((s)>>2)&1) + 4*((s)>>3))

typedef short bfrag __attribute__((ext_vector_type(8)));   // 8 bf16 (4 VGPR)
typedef float f32x4 __attribute__((ext_vector_type(4)));
typedef float f32x16 __attribute__((ext_vector_type(16)));
typedef unsigned short us8 __attribute__((ext_vector_type(8)));

__device__ inline unsigned bf16rne(float x) {
    unsigned u = __builtin_bit_cast(unsigned, x);
    return (u + 0x7fffu + ((u >> 16) & 1u)) >> 16;
}
__device__ inline unsigned packbf2(float a, float b) {
    return bf16rne(a) | (bf16rne(b) << 16);
}
__device__ inline float bf2f(unsigned short u) {
    return __builtin_bit_cast(float, (unsigned)u << 16);
}
__device__ inline void glds16(const unsigned short* g, unsigned char* l) {
    __builtin_amdgcn_global_load_lds(
        (const __attribute__((address_space(1))) unsigned int*)g,
        (__attribute__((address_space(3))) unsigned int*)l, 16, 0, 0);
}

// ---------------------------------------------------------------------------
// conv_v9 (r18 structure): MFMA implicit-GEMM 3x3 conv, pad 1, 32x32x16 bf16,
// W=256 ONLY. Double-buffered LDS + glds staging; cs0/dy0 A-frags loaded
// BEFORE the STAGE(c+1) issue. XCD swizzle: contiguous 32-row band per XCD.
// Interior blocks skip the LDS pre-zero; s_setprio(1) around MFMA clusters.
// SM=true (psf): channel = blockIdx.y (merged 4-channel launch, r19);
// fused softmax(225)+reflect-patch epilogue.
// DO NOT enlarge fragment arrays (r13/r16: spills past ~60 VGPR) and keep
// launch_bounds at 4 blocks/CU for CT=2 (forcing 5 spilled, r13).
// IO: bf16 blocked [cb16][256 y][256 x][16 slots], slot s = ch PERM4(s).
// ---------------------------------------------------------------------------
template<bool RELU, int CT, bool SM>
__global__ __launch_bounds__(256, (CT == 2) ? 4 : 5) void conv_v9(
    const unsigned short* __restrict__ inb, const short* __restrict__ wp,
    const float* __restrict__ bias, unsigned short* __restrict__ ob,
    int C32, int Cout, int COT, int CBmax,
    const float* __restrict__ rawc, float* __restrict__ corr)
{
    int bid = blockIdx.x;
    bid = (bid & 7) * 128 + (bid >> 3);          // XCD swizzle (bijective, 1024 blocks)
    const int y  = bid >> 2;
    const int x0 = (bid & 3) << 6;
    const int t  = threadIdx.x;
    const int l  = t & 63;
    const int col = l & 31, kh = l >> 5;
    const int wv = t >> 6;
    const int ctg0 = wv * CT;

    if (SM) {                                    // merged psf: per-channel bases
        const int ch = blockIdx.y;
        wp   += (size_t)ch * 294912;
        bias += ch * 225;
        rawc += (size_t)ch * 65536;
        corr += (size_t)ch * 65536;
    }

    __shared__ __align__(16) unsigned char sB[2][13824];   // 2 x (3 rows x 72 px x 64B)

    f32x16 acc[CT][2];
#pragma unroll
    for (int ct = 0; ct < CT; ++ct)
#pragma unroll
        for (int n = 0; n < 2; ++n)
#pragma unroll
            for (int i = 0; i < 16; ++i) acc[ct][n][i] = 0.f;

    int ba3[3];
#pragma unroll
    for (int dx = 0; dx < 3; ++dx) {
        int px = col + 3 + dx;
        ba3[dx] = px * 64 + ((kh ^ ((px >> 1) & 3)) << 4);   // cs -> ^32; n=1 -> +2048
    }

    // ---- staging lane constants: 4 glds issues cover 3 rows x 288 units ----
    int srcoff[4];
    bool vmask[4];
#pragma unroll
    for (int i = 0; i < 4; ++i) {
        int q = i * 256 + t;
        bool qv = q < 864;
        int row = q / 288;  if (row > 2) row = 2;
        int qr = q - row * 288;
        int px = qr >> 2, j = qr & 3;
        int u = j ^ ((px >> 1) & 3);
        int gx = x0 - 4 + px;
        int gy = y - 1 + row;
        vmask[i] = qv && ((unsigned)gx < 256u) && ((unsigned)gy < 256u);
        srcoff[i] = (((u >> 1) * 256 + gy) * 256 + gx) * 16 + (u & 1) * 8;
    }

    auto STAGE = [&](int c32, unsigned char* bufb) {
        const int coff = c32 * 2097152;          // 2 cb x 65536 px x 16 ushorts
#pragma unroll
        for (int i = 0; i < 4; ++i)
            if (vmask[i])
                glds16(inb + (srcoff[i] + coff), bufb + (i << 12) + (wv << 10));
    };

    // pre-zero both buffers only when some glds lanes are masked off
    if (x0 == 0 || x0 == 192 || y == 0 || y == 255) {
        for (int i = t; i < 1728; i += 256)
            *(uint4*)(&sB[0][0] + i * 16) = make_uint4(0, 0, 0, 0);
        __syncthreads();
    }

    const bfrag* wA = (const bfrag*)wp;
    const int tstr = C32 * 2 * COT * 64;

    auto LOAD_AF = [&](bfrag (&af)[3][CT], int abase, int dy) {
#pragma unroll
        for (int dx = 0; dx < 3; ++dx)
#pragma unroll
            for (int ct = 0; ct < CT; ++ct)
                af[dx][ct] = wA[abase + ct * 64 + (size_t)(dy * 3 + dx) * tstr];
    };
    auto MFMA_DY = [&](const bfrag (&af)[3][CT], const unsigned char* rp, int csx) {
        __builtin_amdgcn_s_setprio(1);
#pragma unroll
        for (int dx = 0; dx < 3; ++dx) {
            const int ba = ba3[dx] ^ csx;
            bfrag b0 = *(const bfrag*)(rp + ba);
            bfrag b1 = *(const bfrag*)(rp + ba + 2048);
#pragma unroll
            for (int ct = 0; ct < CT; ++ct) {
                acc[ct][0] = __builtin_amdgcn_mfma_f32_32x32x16_bf16(af[dx][ct], b0, acc[ct][0], 0, 0, 0);
                acc[ct][1] = __builtin_amdgcn_mfma_f32_32x32x16_bf16(af[dx][ct], b1, acc[ct][1], 0, 0, 0);
            }
        }
        __builtin_amdgcn_s_setprio(0);
    };

    STAGE(0, sB[0]);
    __syncthreads();
    for (int c32 = 0; c32 < C32; ++c32) {
        const unsigned char* bufp = sB[c32 & 1];
        const int ab0 = (c32 * 2 * COT + ctg0) * 64 + l;
        const int ab1 = ((c32 * 2 + 1) * COT + ctg0) * 64 + l;
        bfrag af0[3][CT];
        LOAD_AF(af0, ab0, 0);                              // BEFORE stage issue
        if (c32 + 1 < C32) STAGE(c32 + 1, sB[(c32 + 1) & 1]);
        MFMA_DY(af0, bufp, 0);                             // cs=0, dy=0
#pragma unroll
        for (int dy = 1; dy < 3; ++dy) {                   // cs=0, dy=1..2
            bfrag af[3][CT];
            LOAD_AF(af, ab0, dy);
            MFMA_DY(af, bufp + dy * 4608, 0);
        }
#pragma unroll
        for (int dy = 0; dy < 3; ++dy) {                   // cs=1, dy=0..2
            bfrag af[3][CT];
            LOAD_AF(af, ab1, dy);
            MFMA_DY(af, bufp + dy * 4608, 32);
        }
        __syncthreads();   // drains next-stage glds + this chunk's LDS reads
    }

    if (SM) {
        // --------- fused softmax(225) + reflect-patch epilogue ---------
        float* sRaw  = (float*)&sB[0][0];        // 1200 floats
        float* sBias = (float*)&sB[0][4800];     // 225 floats
        int*   sOff  = (int*)&sB[0][5700];       // 225 ints: ty*80+tx = t + 65*(t/15)
        float* red   = (float*)&sB[1][0];        // 64 px x 4 g x 3 floats
        for (int i = t; i < 1200; i += 256) {
            int r = i / 80, xx = i - r * 80;
            int gy = y + r - 7;
            gy = gy < 0 ? -gy : (gy > 255 ? 510 - gy : gy);
            int gx = x0 + xx - 7;
            gx = gx < 0 ? -gx : (gx > 255 ? 510 - gx : gx);
            sRaw[i] = rawc[gy * 256 + gx];
        }
        if (t < 225) {
            sBias[t] = bias[t];
            sOff[t]  = t + 65 * (t / 15);
        }
        __syncthreads();

        float pm[2], ps[2], pa[2];
#pragma unroll
        for (int n = 0; n < 2; ++n) {
            float m = -1e30f, s = 0.f, a = 0.f;
            const int xb = col + n * 32;         // local x (gx_local = xb + tx)
#pragma unroll
            for (int ct = 0; ct < CT; ++ct) {
                const f32x16 A = acc[ct][n];
#pragma unroll
                for (int rh = 0; rh < 2; ++rh) {
                    int cb = (ctg0 + ct) * 2 + rh;
#pragma unroll
                    for (int j = 0; j < 8; ++j) {
                        int co = cb * 16 + (j & 3) + 8 * (j >> 2) + 4 * kh;
                        if (co < 225) {
                            float lv = A[rh * 8 + j] + sBias[co];
                            float pv = sRaw[sOff[co] + xb];
                            if (lv > m + 4.f) { float rs = __expf(m - lv); s *= rs; a *= rs; m = lv; }
                            float e = __expf(lv - m);
                            s += e; a += e * pv;
                        }
                    }
                }
            }
            // in-wave kh merge (lanes l <-> l^32 hold same px, other kh half)
            float mo = __shfl_xor(m, 32), so = __shfl_xor(s, 32), ao = __shfl_xor(a, 32);
            float M = fmaxf(m, mo);
            float e0 = __expf(m - M), e1 = __expf(mo - M);
            pm[n] = M;
            ps[n] = s * e0 + so * e1;
            pa[n] = a * e0 + ao * e1;
        }
        // cross-wave merge: 4 groups (wv), px = col + n*32
        if (kh == 0) {
#pragma unroll
            for (int n = 0; n < 2; ++n) {
                int px = col + n * 32;
                red[(px * 4 + wv) * 3 + 0] = pm[n];
                red[(px * 4 + wv) * 3 + 1] = ps[n];
                red[(px * 4 + wv) * 3 + 2] = pa[n];
            }
        }
        __syncthreads();
        if (t < 64) {
            float m = red[(t * 4) * 3], s = red[(t * 4) * 3 + 1], a = red[(t * 4) * 3 + 2];
#pragma unroll
            for (int gg = 1; gg < 4; ++gg) {
                float mg = red[(t * 4 + gg) * 3], sg = red[(t * 4 + gg) * 3 + 1], ag = red[(t * 4 + gg) * 3 + 2];
                float M = fmaxf(m, mg);
                float s0 = __expf(m - M), s1 = __expf(mg - M);
                s = s * s0 + sg * s1;
                a = a * s0 + ag * s1;
                m = M;
            }
            corr[y * 256 + x0 + t] = a / s;
        }
    } else {
        // epilogue: C/D col = l&31 (px), row = (reg&3)+8*(reg>>2)+4*kh
#pragma unroll
        for (int ct = 0; ct < CT; ++ct) {
            const int ctg = ctg0 + ct;
#pragma unroll
            for (int n = 0; n < 2; ++n) {
                const int xx = x0 + col + n * 32;
                const f32x16 A = acc[ct][n];
#pragma unroll
                for (int rh = 0; rh < 2; ++rh) {
                    int cb = ctg * 2 + rh;
                    if (cb >= CBmax) continue;
                    unsigned wd[4];
#pragma unroll
                    for (int jp = 0; jp < 4; ++jp) {
                        float vv[2];
#pragma unroll
                        for (int e = 0; e < 2; ++e) {
                            int j = jp * 2 + e;
                            int co = cb * 16 + (j & 3) + 8 * (j >> 2) + 4 * kh;
                            float bv = (co < Cout) ? bias[co] : 0.f;
                            float v = A[rh * 8 + j] + bv;
                            if (RELU) v = fmaxf(v, 0.f);
                            vv[e] = v;
                        }
                        wd[jp] = packbf2(vv[0], vv[1]);
                    }
                    *(uint4*)(ob + ((((size_t)cb << 8) + y) * 256 + xx) * 16 + (kh << 3)) =
                        make_uint4(wd[0], wd[1], wd[2], wd[3]);
                }
            }
        }
    }
}

// ---------------------------------------------------------------------------
// conv_v4 (reg-staged, generic W/RS) — kept for the freq-domain convs.
// ---------------------------------------------------------------------------
template<bool RELU, bool OUT_BF16, int CT>
__global__ __launch_bounds__(256, 3) void conv_v4(
    const unsigned short* __restrict__ inb, const short* __restrict__ wp,
    const float* __restrict__ bias, void* __restrict__ outv,
    int C32, int Cout, int COT, int W, int RSg, int CBmax)
{
    const int tilesx = (W + 127) >> 7;
    const int y  = blockIdx.x / tilesx;
    const int x0 = (blockIdx.x % tilesx) << 7;
    const int t  = threadIdx.x;
    const int l  = t & 63;
    const int col = l & 31, kh = l >> 5;
    const int wv = t >> 6;
    const int wct = wv & 1, wpt = wv >> 1;
    const int ctg0 = (blockIdx.y * 2 + wct) * CT;

    __shared__ __align__(16) unsigned char sB[26112];

    f32x16 acc[CT][2];
#pragma unroll
    for (int ct = 0; ct < CT; ++ct)
#pragma unroll
        for (int n = 0; n < 2; ++n)
#pragma unroll
            for (int i = 0; i < 16; ++i) acc[ct][n][i] = 0.f;

    int ba3[3];
#pragma unroll
    for (int dx = 0; dx < 3; ++dx) {
        int px = wpt * 64 + col + 3 + dx;
        ba3[dx] = px * 64 + ((kh ^ ((px >> 1) & 3)) << 4);
    }

    const int pxm = (t & 127) + 4, thalf = t >> 7;
    const int gxm = x0 + (t & 127);
    const bool gxok = gxm < W;
    const int offm_e = pxm * 64 + ((thalf ^ ((pxm >> 1) & 3)) << 4);
    const int hr = t >> 5, hj = t & 31, hg = hj >> 3, hp = hj & 7;
    const int hslot = hp + ((hp >> 2) << 7);
    const int hgx = x0 - 4 + hslot;
    const int hoff = hr * 8704 + hslot * 64 + ((hg ^ ((hslot >> 1) & 3)) << 4);
    const int hgy = y + hr - 1;
    const bool hok = (t < 96) && ((unsigned)hgy < 256u) && ((unsigned)hgx < (unsigned)W);

    auto STAGE = [&](int c32) {
        const int cb0 = c32 << 1;
#pragma unroll
        for (int k = 0; k < 6; ++k) {
            const int r = k >> 1;
            const int cb = cb0 + (k & 1);
            const int gy = y + r - 1;
            uint4 v = make_uint4(0, 0, 0, 0);
            if (gxok && (unsigned)gy < 256u)
                v = *(const uint4*)(inb + ((((size_t)cb << 8) + gy) * RSg + gxm) * 16 + (thalf << 3));
            *(uint4*)(sB + r * 8704 + (offm_e ^ ((k & 1) << 5))) = v;
        }
        if (t < 96) {
            uint4 v = make_uint4(0, 0, 0, 0);
            if (hok) v = *(const uint4*)(inb + ((((size_t)(cb0 + (hg >> 1)) << 8) + hgy) * RSg + hgx) * 16 + ((hg & 1) << 3));
            *(uint4*)(sB + hoff) = v;
        }
    };

    const bfrag* wA = (const bfrag*)wp;
    const int tstr = C32 * 2 * COT * 64;

    STAGE(0);
    __syncthreads();
    for (int c32 = 0; c32 < C32; ++c32) {
#pragma unroll 1
        for (int cs = 0; cs < 2; ++cs) {
            const int abase = ((c32 * 2 + cs) * COT + ctg0) * 64 + l;
            const int csx = cs << 5;
#pragma unroll
            for (int dy = 0; dy < 3; ++dy) {
                bfrag af[3][CT];
#pragma unroll
                for (int dx = 0; dx < 3; ++dx)
#pragma unroll
                    for (int ct = 0; ct < CT; ++ct)
                        af[dx][ct] = wA[abase + ct * 64 + (size_t)(dy * 3 + dx) * tstr];
                const unsigned char* rp = sB + dy * 8704;
#pragma unroll
                for (int dx = 0; dx < 3; ++dx) {
                    const int ba = ba3[dx] ^ csx;
                    bfrag b0 = *(const bfrag*)(rp + ba);
                    bfrag b1 = *(const bfrag*)(rp + ba + 2048);
#pragma unroll
                    for (int ct = 0; ct < CT; ++ct) {
                        acc[ct][0] = __builtin_amdgcn_mfma_f32_32x32x16_bf16(af[dx][ct], b0, acc[ct][0], 0, 0, 0);
                        acc[ct][1] = __builtin_amdgcn_mfma_f32_32x32x16_bf16(af[dx][ct], b1, acc[ct][1], 0, 0, 0);
                    }
                }
            }
        }
        __syncthreads();
        if (c32 + 1 < C32) { STAGE(c32 + 1); __syncthreads(); }
    }

    const int xBase = x0 + wpt * 64 + col;
#pragma unroll
    for (int ct = 0; ct < CT; ++ct) {
        const int ctg = ctg0 + ct;
#pragma unroll
        for (int n = 0; n < 2; ++n) {
            int xx = xBase + n * 32;
            if (xx >= W) continue;
            const f32x16 A = acc[ct][n];
            if (OUT_BF16) {
                unsigned short* ob = (unsigned short*)outv;
#pragma unroll
                for (int rh = 0; rh < 2; ++rh) {
                    int cb = ctg * 2 + rh;
                    if (cb >= CBmax) continue;
                    unsigned wd[4];
#pragma unroll
                    for (int jp = 0; jp < 4; ++jp) {
                        float vv[2];
#pragma unroll
                        for (int e = 0; e < 2; ++e) {
                            int j = jp * 2 + e;
                            int co = cb * 16 + (j & 3) + 8 * (j >> 2) + 4 * kh;
                            float bv = (co < Cout) ? bias[co] : 0.f;
                            float v = A[rh * 8 + j] + bv;
                            if (RELU) v = fmaxf(v, 0.f);
                            vv[e] = v;
                        }
                        wd[jp] = packbf2(vv[0], vv[1]);
                    }
                    *(uint4*)(ob + ((((size_t)cb << 8) + y) * RSg + xx) * 16 + (kh << 3)) =
                        make_uint4(wd[0], wd[1], wd[2], wd[3]);
                }
            } else {
                float* of = (float*)outv;
#pragma unroll
                for (int reg = 0; reg < 16; ++reg) {
                    int co = ctg * 32 + (reg & 3) + 8 * (reg >> 2) + 4 * kh;
                    if (co < Cout) {
                        float v = A[reg] + bias[co];
                        if (RELU) v = fmaxf(v, 0.f);
                        of[(((size_t)co << 8) + y) * RSg + xx] = v;
                    }
                }
            }
        }
    }
}

// ---------------------------------------------------------------------------
// Merged weight repack: 9 repack_wA jobs in ONE launch.
// ---------------------------------------------------------------------------
struct RepackJob { const float* w; unsigned short* o; int Cin, C32, Cout, COT, blk0, nblk; };
struct RepackJobs { RepackJob j[9]; };

__global__ __launch_bounds__(256) void repack_multi(RepackJobs J)
{
    int b = blockIdx.x;
    int ji = 0;
#pragma unroll
    for (int k = 1; k < 9; ++k) if (b >= J.j[k].blk0) ji = k;
    const RepackJob jb = J.j[ji];
    int rb = b - jb.blk0;
    int total = 9 * jb.C32 * 2 * jb.COT * 512;
    for (int i = rb * 256 + threadIdx.x; i < total; i += jb.nblk * 256) {
        int j = i & 7;
        int l = (i >> 3) & 63;
        int rest = i >> 9;
        int ct = rest % jb.COT; rest /= jb.COT;
        int cs = rest & 1; rest >>= 1;
        int c32 = rest % jb.C32;
        int tap = rest / jb.C32;
        int co = ct * 32 + (l & 31);
        int s = ((l >> 5) << 3) + j;
        int ci = c32 * 32 + cs * 16 + PERM4(s);
        float v = (co < jb.Cout && ci < jb.Cin) ? jb.w[((size_t)co * jb.Cin + ci) * 9 + tap] : 0.f;
        jb.o[i] = (unsigned short)bf16rne(v);
    }
}

// fp32 NCHW [C][256][256] -> bf16 blocked [CB][y][x][16] with PERM slots
__global__ __launch_bounds__(256) void cvt_blocked(
    const float* __restrict__ src, unsigned short* __restrict__ dst, int C)
{
    int cb = blockIdx.x >> 8;
    int y  = blockIdx.x & 255;
    int x  = threadIdx.x;
    unsigned wd[8];
#pragma unroll
    for (int q = 0; q < 8; ++q) {
        float v[2];
#pragma unroll
        for (int e = 0; e < 2; ++e) {
            int s = q * 2 + e;
            int ci = (cb << 4) + PERM4(s);
            v[e] = (ci < C) ? src[((size_t)ci * 256 + y) * 256 + x] : 0.f;
        }
        wd[q] = packbf2(v[0], v[1]);
    }
    unsigned short* dp = dst + (((size_t)cb << 16) + (y << 8) + x) * 16;
    *(uint4*)dp = make_uint4(wd[0], wd[1], wd[2], wd[3]);
    *(uint4*)(dp + 8) = make_uint4(wd[4], wd[5], wd[6], wd[7]);
}

// ---------------------------------------------------------------------------
// Refinement
// ---------------------------------------------------------------------------
__global__ __launch_bounds__(256) void repack_wr2(
    const float* __restrict__ cw2, unsigned short* __restrict__ o)
{
    int i = blockIdx.x * 256 + threadIdx.x;
    if (i >= 10240) return;
    int k = i & 31, rest = i >> 5;
    int co = rest & 15;
    int kt = (rest >> 4) % 5;
    int ch = rest / 80;
    int tap = 2 * kt + (k >= 16 ? 1 : 0), ci = k & 15;
    float v = 0.f;
    if (tap < 9) v = cw2[(((size_t)ch * 16 + co) * 16 + ci) * 9 + tap];
    o[i] = (unsigned short)bf16rne(v);
}

__global__ __launch_bounds__(256) void refine1_kernel(
    const float* __restrict__ corrected, const float* __restrict__ cw1,
    const float* __restrict__ cb1, unsigned short* __restrict__ h1b)
{
    const int c = blockIdx.x >> 8;
    const int y = blockIdx.x & 255;
    const int t = threadIdx.x;
    __shared__ float sIn[3][258];
    __shared__ float sW[144];
    __shared__ float sBv[16];
    if (t < 144) sW[t] = cw1[c * 144 + t];
    if (t >= 144 && t < 160) sBv[t - 144] = cb1[c * 16 + (t - 144)];
    for (int i = t; i < 774; i += 256) {
        int r = i / 258, xx = i % 258;
        int gy = y + r - 1, gx = xx - 1;
        sIn[r][xx] = ((unsigned)gy < 256u && (unsigned)gx < 256u)
                   ? corrected[((size_t)c * 256 + gy) * 256 + gx] : 0.f;
    }
    __syncthreads();
    float a[9];
#pragma unroll
    for (int dy = 0; dy < 3; ++dy)
#pragma unroll
        for (int dx = 0; dx < 3; ++dx) a[dy * 3 + dx] = sIn[dy][t + dx];
    unsigned short ov[16];
#pragma unroll
    for (int co = 0; co < 16; ++co) {
        float acc = sBv[co];
#pragma unroll
        for (int tap = 0; tap < 9; ++tap) acc += a[tap] * sW[co * 9 + tap];
        acc = fmaxf(acc, 0.f);
        ov[co] = (unsigned short)bf16rne(acc);
    }
    unsigned short* op = h1b + ((((size_t)c * 256 + y) * 256 + t) << 4);
    *(uint4*)op = *(uint4*)ov;
    *(uint4*)(op + 8) = *(uint4*)(ov + 8);
}

__global__ __launch_bounds__(256) void refine2_mfma(
    const unsigned short* __restrict__ h1b, const unsigned short* __restrict__ wr2,
    const float* __restrict__ cb2, unsigned short* __restrict__ h2b)
{
    const int c = blockIdx.x >> 8;
    const int y = blockIdx.x & 255;
    const int t = threadIdx.x;
    const int l15 = t & 15, lg = (t >> 4) & 3, wv = t >> 6;

    __shared__ __align__(16) unsigned char sA[3 * 258 * 32];

    for (int i = t; i < 1548; i += 256) {
        int r = i / 516, u = i % 516;
        int px = u >> 1, half = u & 1;
        int gy = y + r - 1, gx = px - 1;
        uint4 v = make_uint4(0, 0, 0, 0);
        if ((unsigned)gy < 256u && (unsigned)gx < 256u)
            v = *(const uint4*)(h1b + ((((size_t)c * 256 + gy) * 256 + gx) << 4) + (half << 3));
        *(uint4*)(sA + r * 8256 + px * 32 + ((half ^ ((px >> 2) & 1)) << 4)) = v;
    }
    __syncthreads();

    f32x4 acc[4];
#pragma unroll
    for (int n = 0; n < 4; ++n) acc[n] = (f32x4){0.f, 0.f, 0.f, 0.f};
    const bfrag* wf = (const bfrag*)(wr2 + (size_t)c * 2560);
    const int strip = wv * 64;
#pragma unroll
    for (int kt = 0; kt < 5; ++kt) {
        bfrag a = wf[(kt * 16 + l15) * 4 + lg];
        int tap1 = 2 * kt + 1; if (tap1 > 8) tap1 = 8;
        int tap = (lg < 2) ? (2 * kt) : tap1;
        int dy = tap / 3, dx = tap % 3;
#pragma unroll
        for (int n = 0; n < 4; ++n) {
            int pxs = strip + n * 16 + l15 + dx;
            bfrag b = *(const bfrag*)(sA + dy * 8256 + pxs * 32 +
                                      (((lg & 1) ^ ((pxs >> 2) & 1)) << 4));
            acc[n] = __builtin_amdgcn_mfma_f32_16x16x32_bf16(a, b, acc[n], 0, 0, 0);
        }
    }

#pragma unroll
    for (int n = 0; n < 4; ++n) {
        int px = strip + n * 16 + l15;
        unsigned short ov[4];
#pragma unroll
        for (int r = 0; r < 4; ++r) {
            int co = lg * 4 + r;
            float v = acc[n][r] + cb2[c * 16 + co];
            v = fmaxf(v, 0.f);
            ov[r] = (unsigned short)bf16rne(v);
        }
        *(ushort4*)(h2b + ((((size_t)c * 256 + y) * 256 + px) << 4) + lg * 4) = *(ushort4*)ov;
    }
}

__global__ __launch_bounds__(256) void refine3_kernel(
    const unsigned short* __restrict__ h2b, const float* __restrict__ cw3,
    const float* __restrict__ cb3, const float* __restrict__ raw,
    float* __restrict__ out)
{
    const int c = blockIdx.x >> 8;
    const int y = blockIdx.x & 255;
    const int t = threadIdx.x;
    __shared__ __align__(16) unsigned char sA[3 * 258 * 32];
    __shared__ float sW[144];
    if (t < 144) sW[t] = cw3[c * 144 + t];
    for (int i = t; i < 1548; i += 256) {
        int r = i / 516, u = i % 516;
        int px = u >> 1, half = u & 1;
        int gy = y + r - 1, gx = px - 1;
        uint4 v = make_uint4(0, 0, 0, 0);
        if ((unsigned)gy < 256u && (unsigned)gx < 256u)
            v = *(const uint4*)(h2b + ((((size_t)c * 256 + gy) * 256 + gx) << 4) + (half << 3));
        *(uint4*)(sA + r * 8256 + px * 32 + ((half ^ ((px >> 2) & 1)) << 4)) = v;
    }
    __syncthreads();
    float acc = cb3[c];
#pragma unroll
    for (int tap = 0; tap < 9; ++tap) {
        int dy = tap / 3, dx = tap % 3;
        int px = t + dx;
        const unsigned char* p = sA + dy * 8256 + px * 32;
        int sw = ((px >> 2) & 1) << 4;
        us8 h0 = *(const us8*)(p + (sw ^ 0));
        us8 h1 = *(const us8*)(p + (sw ^ 16));
#pragma unroll
        for (int j = 0; j < 8; ++j) acc += bf2f(h0[j]) * sW[j * 9 + tap];
#pragma unroll
        for (int j = 0; j < 8; ++j) acc += bf2f(h1[j]) * sW[(8 + j) * 9 + tap];
    }
    size_t idx = ((size_t)c * 256 + y) * 256 + t;
    float v = raw[idx] + acc;
    out[idx] = fminf(fmaxf(v, 0.f), 1.f);
}

// ---------------------------------------------------------------------------
// DFT kernels
// ---------------------------------------------------------------------------
__global__ __launch_bounds__(256) void rdft_row_kernel(
    const float* __restrict__ x, float2* __restrict__ z)
{
    int cy = blockIdx.x;
    __shared__ float row[256];
    __shared__ float ct[256], st[256];
    int t = threadIdx.x;
    row[t] = x[cy * 256 + t];
    float a = (2.0f * PI_F / 256.0f) * (float)t;
    ct[t] = cosf(a);
    st[t] = sinf(a);
    __syncthreads();
    if (t < 129) {
        float re = 0.f, im = 0.f;
        int idx = 0;
        for (int n = 0; n < 256; ++n) {
            float v = row[n];
            re += v * ct[idx];
            im -= v * st[idx];
            idx = (idx + t) & 255;
        }
        z[cy * 129 + t] = make_float2(re, im);
    }
}

__global__ __launch_bounds__(256) void dft_col_fwd2(
    const float2* __restrict__ z, unsigned short* __restrict__ fri16)
{
    int c  = blockIdx.x >> 8;
    int k1 = blockIdx.x & 255;
    __shared__ float ct[256], st[256];
    int t = threadIdx.x;
    float a = (2.0f * PI_F / 256.0f) * (float)t;
    ct[t] = cosf(a);
    st[t] = sinf(a);
    __syncthreads();
    if (t < 129) {
        float re = 0.f, im = 0.f;
        int idx = 0;
        for (int n1 = 0; n1 < 256; ++n1) {
            float2 zv = z[(c * 256 + n1) * 129 + t];
            float cw = ct[idx], sw = st[idx];
            re += zv.x * cw + zv.y * sw;
            im += zv.y * cw - zv.x * sw;
            idx = (idx + k1) & 255;
        }
        const float sc = 1.0f / 256.0f;
        size_t base = ((size_t)k1 * 132 + t) * 16;
        fri16[base + c]     = (unsigned short)bf16rne(re * sc);
        fri16[base + 8 + c] = (unsigned short)bf16rne(im * sc);
    }
}

// fused inverse: column inverse DFT (k1 -> n1) into LDS, then Hermitian row
// inverse (k2 -> n2) and accumulate into corrected. One block per (c, n1).
__global__ __launch_bounds__(256) void idft_fused_kernel(
    const float* __restrict__ g, float* __restrict__ corrected)
{
    int c  = blockIdx.x >> 8;
    int n1 = blockIdx.x & 255;
    __shared__ float2 yrow[129];
    __shared__ float ct[256], st[256];
    int t = threadIdx.x;
    float a = (2.0f * PI_F / 256.0f) * (float)t;
    ct[t] = cosf(a);
    st[t] = sinf(a);
    __syncthreads();
    if (t < 129) {
        float re = 0.f, im = 0.f;
        int idx = 0;
        for (int k1 = 0; k1 < 256; ++k1) {
            float gr = g[((size_t)c * 256 + k1) * 132 + t];
            float gi = g[((size_t)(4 + c) * 256 + k1) * 132 + t];
            float cw = ct[idx], sw = st[idx];
            re += gr * cw - gi * sw;
            im += gi * cw + gr * sw;
            idx = (idx + n1) & 255;
        }
        yrow[t] = make_float2(re, im);
    }
    __syncthreads();
    float acc = yrow[0].x + ((t & 1) ? -yrow[128].x : yrow[128].x);
    int idx = t;
    for (int k = 1; k <= 127; ++k) {
        float2 yv = yrow[k];
        acc += 2.0f * (yv.x * ct[idx] - yv.y * st[idx]);
        idx = (idx + t) & 255;
    }
    corrected[c * 65536 + n1 * 256 + t] += acc * (1.0f / 256.0f);
}

// ---------------------------------------------------------------------------
extern "C" void kernel_launch(void* const* d_in, const int* in_sizes, int n_in,
                              void* d_out, int out_size, void* d_ws, size_t ws_size,
                              hipStream_t stream)
{
    const float* raw = (const float*)d_in[0];
    const float* ab  = (const float*)d_in[1];
    const float* pw1 = (const float*)d_in[2];  const float* pb1 = (const float*)d_in[3];
    const float* pw2 = (const float*)d_in[4];  const float* pb2 = (const float*)d_in[5];
    const float* pw3 = (const float*)d_in[6];  const float* pb3 = (const float*)d_in[7];
    const float* fw1 = (const float*)d_in[8];  const float* fb1 = (const float*)d_in[9];
    const float* fw2 = (const float*)d_in[10]; const float* fb2 = (const float*)d_in[11];
    const float* fw3 = (const float*)d_in[12]; const float* fb3 = (const float*)d_in[13];
    const float* cw1 = (const float*)d_in[14]; const float* cb1 = (const float*)d_in[15];
    const float* cw2 = (const float*)d_in[16]; const float* cb2 = (const float*)d_in[17];
    const float* cw3 = (const float*)d_in[18]; const float* cb3 = (const float*)d_in[19];
    float* out = (float*)d_out;

    char* B = (char*)d_ws;
    unsigned short* h1b     = (unsigned short*)(B);              // 33,554,432 B (16 cb)
    unsigned short* h2b     = (unsigned short*)(B + 33554432);   // 16,777,216 B (8 cb)
    unsigned short* h1r     = (unsigned short*)(B + 33554432);   // alias (after psf)
    unsigned short* h2r     = (unsigned short*)(B + 41943040);
    float* corrected = (float*)(B + 50331648);                   // 1,048,576 B
    float2* zbuf     = (float2*)(B + 51380224);                  // 2,113,536 B
    unsigned short* fri16 = (unsigned short*)(B + 53493760);     // 2,162,688 B (2 cb, RS 132)
    unsigned short* g1b   = (unsigned short*)(B + 55656448);     // 4,325,376 B (4 cb)
    unsigned short* g2b   = (unsigned short*)(B + 59981824);     // 4,325,376 B
    float* gf        = (float*)(B + 64307200);                   // 1,081,344 B
    unsigned short* rw1  = (unsigned short*)(B + 65388544);      // 589,824 B
    unsigned short* rw2  = (unsigned short*)(B + 65978368);      // 589,824 B
    unsigned short* rw3  = (unsigned short*)(B + 66568192);      // 4 x 589,824 B
    unsigned short* rwf1 = (unsigned short*)(B + 68927488);      // 36,864 B
    unsigned short* rwf2 = (unsigned short*)(B + 68964352);      // 73,728 B
    unsigned short* rwf3 = (unsigned short*)(B + 69038080);      // 73,728 B
    unsigned short* wr2r = (unsigned short*)(B + 69111808);      // 20,480 B
    unsigned short* ab16 = (unsigned short*)(B + 69132288);      // 16,777,216 B

    dim3 blk(256);

    // merged weight repacks (one launch) + remaining converts
    RepackJobs J;
    J.j[0] = { pw1,                    rw1,                128, 4, 256, 8,    0, 512 };
    J.j[1] = { pw2,                    rw2,                256, 8, 128, 4,  512, 512 };
    J.j[2] = { pw3 + 0 * 259200,       rw3 + 0 * 294912,   128, 4, 225, 8, 1024, 512 };
    J.j[3] = { pw3 + 1 * 259200,       rw3 + 1 * 294912,   128, 4, 225, 8, 1536, 512 };
    J.j[4] = { pw3 + 2 * 259200,       rw3 + 2 * 294912,   128, 4, 225, 8, 2048, 512 };
    J.j[5] = { pw3 + 3 * 259200,       rw3 + 3 * 294912,   128, 4, 225, 8, 2560, 512 };
    J.j[6] = { fw1,                    rwf1,                 8, 1,  64, 2, 3072,  64 };
    J.j[7] = { fw2,                    rwf2,                64, 2,  64, 2, 3136, 128 };
    J.j[8] = { fw3,                    rwf3,                64, 2,   8, 2, 3264, 128 };
    repack_multi<<<3392, blk, 0, stream>>>(J);
    repack_wr2<<<40, blk, 0, stream>>>(cw2, wr2r);
    cvt_blocked<<<2048, blk, 0, stream>>>(ab, ab16, 128);

    // conv1: ab16(128) -> h1b(256), relu   [block = 256co x 64px, CT=2]
    conv_v9<true, 2, false><<<1024, blk, 0, stream>>>(
        ab16, (const short*)rw1, pb1, h1b, 4, 256, 8, 16, nullptr, nullptr);
    // conv2: h1b(256) -> h2b(128), relu    [block = 128co x 64px, CT=1]
    conv_v9<true, 1, false><<<1024, blk, 0, stream>>>(
        h1b, (const short*)rw2, pb2, h2b, 8, 128, 4, 8, nullptr, nullptr);
    // psf conv with FUSED softmax+patch epilogue, all 4 channels in ONE launch
    conv_v9<false, 2, true><<<dim3(1024, 4), blk, 0, stream>>>(
        h2b, (const short*)rw3, pb3, h1b, 4, 225, 8, 15, raw, corrected);
    // forward rfft2 (ortho)
    rdft_row_kernel<<<1024, blk, 0, stream>>>(corrected, zbuf);
    hipMemsetAsync(fri16, 0, 2162688, stream);
    dft_col_fwd2<<<1024, blk, 0, stream>>>(zbuf, fri16);
    // freq-domain convs (W=129, RS=132)
    conv_v4<true, true, 1><<<dim3(512, 1), blk, 0, stream>>>(
        fri16, (const short*)rwf1, fb1, g1b, 1, 64, 2, 129, 132, 4);
    conv_v4<true, true, 1><<<dim3(512, 1), blk, 0, stream>>>(
        g1b, (const short*)rwf2, fb2, g2b, 2, 64, 2, 129, 132, 4);
    conv_v4<false, false, 1><<<dim3(512, 1), blk, 0, stream>>>(
        g2b, (const short*)rwf3, fb3, gf, 2, 8, 2, 129, 132, 0);
    // fused inverse irfft2 (ortho), accumulate into corrected
    idft_fused_kernel<<<1024, blk, 0, stream>>>(gf, corrected);
    // per-channel refinement, fused final clip
    refine1_kernel<<<1024, blk, 0, stream>>>(corrected, cw1, cb1, h1r);
    refine2_mfma<<<1024, blk, 0, stream>>>(h1r, wr2r, cb2, h2r);
    refine3_kernel<<<1024, blk, 0, stream>>>(h2r, cw3, cb3, raw, out);
}

// Round 20
// 404.106 us; speedup vs baseline: 2.7123x; 1.0691x over previous
//
#include <hip/hip_runtime.h>
#include <hip/hip_bf16.h>
#include <math.h>

#define PI_F 3.14159265358979323846f
// ci16 permutation (involution, swaps bits 2<->3): storage slot s holds channel PERM4(s)
#define PERM4(s) ((((s)&3)) + 8*(((s)>>2)&1) + 4*((s)>>3))

typedef short bfrag __attribute__((ext_vector_type(8)));   // 8 bf16 (4 VGPR)
typedef float f32x4 __attribute__((ext_vector_type(4)));
typedef float f32x16 __attribute__((ext_vector_type(16)));
typedef unsigned short us8 __attribute__((ext_vector_type(8)));

__device__ inline unsigned bf16rne(float x) {
    unsigned u = __builtin_bit_cast(unsigned, x);
    return (u + 0x7fffu + ((u >> 16) & 1u)) >> 16;
}
__device__ inline unsigned packbf2(float a, float b) {
    return bf16rne(a) | (bf16rne(b) << 16);
}
__device__ inline float bf2f(unsigned short u) {
    return __builtin_bit_cast(float, (unsigned)u << 16);
}
__device__ inline void glds16(const unsigned short* g, unsigned char* l) {
    __builtin_amdgcn_global_load_lds(
        (const __attribute__((address_space(1))) unsigned int*)g,
        (__attribute__((address_space(3))) unsigned int*)l, 16, 0, 0);
}

// ---------------------------------------------------------------------------
// conv_v9 (r18/r19 structure): MFMA implicit-GEMM 3x3 conv, pad 1, 32x32x16
// bf16, W=256 ONLY. Double-buffered LDS + glds staging; cs0/dy0 A-frags
// loaded BEFORE the STAGE(c+1) issue. XCD swizzle: contiguous 32-row band per
// XCD. Interior blocks skip the LDS pre-zero; s_setprio(1) around MFMA.
// SM=true (psf): channel = blockIdx.y (merged 4-channel launch);
// fused softmax(225)+reflect-patch epilogue.
// DO NOT enlarge fragment arrays (r13/r16: spills past ~60 VGPR) and keep
// launch_bounds at 4 blocks/CU for CT=2 (forcing 5 spilled, r13).
// IO: bf16 blocked [cb16][256 y][256 x][16 slots], slot s = ch PERM4(s).
// ---------------------------------------------------------------------------
template<bool RELU, int CT, bool SM>
__global__ __launch_bounds__(256, (CT == 2) ? 4 : 5) void conv_v9(
    const unsigned short* __restrict__ inb, const short* __restrict__ wp,
    const float* __restrict__ bias, unsigned short* __restrict__ ob,
    int C32, int Cout, int COT, int CBmax,
    const float* __restrict__ rawc, float* __restrict__ corr)
{
    int bid = blockIdx.x;
    bid = (bid & 7) * 128 + (bid >> 3);          // XCD swizzle (bijective, 1024 blocks)
    const int y  = bid >> 2;
    const int x0 = (bid & 3) << 6;
    const int t  = threadIdx.x;
    const int l  = t & 63;
    const int col = l & 31, kh = l >> 5;
    const int wv = t >> 6;
    const int ctg0 = wv * CT;

    if (SM) {                                    // merged psf: per-channel bases
        const int ch = blockIdx.y;
        wp   += (size_t)ch * 294912;
        bias += ch * 225;
        rawc += (size_t)ch * 65536;
        corr += (size_t)ch * 65536;
    }

    __shared__ __align__(16) unsigned char sB[2][13824];   // 2 x (3 rows x 72 px x 64B)

    f32x16 acc[CT][2];
#pragma unroll
    for (int ct = 0; ct < CT; ++ct)
#pragma unroll
        for (int n = 0; n < 2; ++n)
#pragma unroll
            for (int i = 0; i < 16; ++i) acc[ct][n][i] = 0.f;

    int ba3[3];
#pragma unroll
    for (int dx = 0; dx < 3; ++dx) {
        int px = col + 3 + dx;
        ba3[dx] = px * 64 + ((kh ^ ((px >> 1) & 3)) << 4);   // cs -> ^32; n=1 -> +2048
    }

    // ---- staging lane constants: 4 glds issues cover 3 rows x 288 units ----
    int srcoff[4];
    bool vmask[4];
#pragma unroll
    for (int i = 0; i < 4; ++i) {
        int q = i * 256 + t;
        bool qv = q < 864;
        int row = q / 288;  if (row > 2) row = 2;
        int qr = q - row * 288;
        int px = qr >> 2, j = qr & 3;
        int u = j ^ ((px >> 1) & 3);
        int gx = x0 - 4 + px;
        int gy = y - 1 + row;
        vmask[i] = qv && ((unsigned)gx < 256u) && ((unsigned)gy < 256u);
        srcoff[i] = (((u >> 1) * 256 + gy) * 256 + gx) * 16 + (u & 1) * 8;
    }

    auto STAGE = [&](int c32, unsigned char* bufb) {
        const int coff = c32 * 2097152;          // 2 cb x 65536 px x 16 ushorts
#pragma unroll
        for (int i = 0; i < 4; ++i)
            if (vmask[i])
                glds16(inb + (srcoff[i] + coff), bufb + (i << 12) + (wv << 10));
    };

    // pre-zero both buffers only when some glds lanes are masked off
    if (x0 == 0 || x0 == 192 || y == 0 || y == 255) {
        for (int i = t; i < 1728; i += 256)
            *(uint4*)(&sB[0][0] + i * 16) = make_uint4(0, 0, 0, 0);
        __syncthreads();
    }

    const bfrag* wA = (const bfrag*)wp;
    const int tstr = C32 * 2 * COT * 64;

    auto LOAD_AF = [&](bfrag (&af)[3][CT], int abase, int dy) {
#pragma unroll
        for (int dx = 0; dx < 3; ++dx)
#pragma unroll
            for (int ct = 0; ct < CT; ++ct)
                af[dx][ct] = wA[abase + ct * 64 + (size_t)(dy * 3 + dx) * tstr];
    };
    auto MFMA_DY = [&](const bfrag (&af)[3][CT], const unsigned char* rp, int csx) {
        __builtin_amdgcn_s_setprio(1);
#pragma unroll
        for (int dx = 0; dx < 3; ++dx) {
            const int ba = ba3[dx] ^ csx;
            bfrag b0 = *(const bfrag*)(rp + ba);
            bfrag b1 = *(const bfrag*)(rp + ba + 2048);
#pragma unroll
            for (int ct = 0; ct < CT; ++ct) {
                acc[ct][0] = __builtin_amdgcn_mfma_f32_32x32x16_bf16(af[dx][ct], b0, acc[ct][0], 0, 0, 0);
                acc[ct][1] = __builtin_amdgcn_mfma_f32_32x32x16_bf16(af[dx][ct], b1, acc[ct][1], 0, 0, 0);
            }
        }
        __builtin_amdgcn_s_setprio(0);
    };

    STAGE(0, sB[0]);
    __syncthreads();
    for (int c32 = 0; c32 < C32; ++c32) {
        const unsigned char* bufp = sB[c32 & 1];
        const int ab0 = (c32 * 2 * COT + ctg0) * 64 + l;
        const int ab1 = ((c32 * 2 + 1) * COT + ctg0) * 64 + l;
        bfrag af0[3][CT];
        LOAD_AF(af0, ab0, 0);                              // BEFORE stage issue
        if (c32 + 1 < C32) STAGE(c32 + 1, sB[(c32 + 1) & 1]);
        MFMA_DY(af0, bufp, 0);                             // cs=0, dy=0
#pragma unroll
        for (int dy = 1; dy < 3; ++dy) {                   // cs=0, dy=1..2
            bfrag af[3][CT];
            LOAD_AF(af, ab0, dy);
            MFMA_DY(af, bufp + dy * 4608, 0);
        }
#pragma unroll
        for (int dy = 0; dy < 3; ++dy) {                   // cs=1, dy=0..2
            bfrag af[3][CT];
            LOAD_AF(af, ab1, dy);
            MFMA_DY(af, bufp + dy * 4608, 32);
        }
        __syncthreads();   // drains next-stage glds + this chunk's LDS reads
    }

    if (SM) {
        // --------- fused softmax(225) + reflect-patch epilogue ---------
        float* sRaw  = (float*)&sB[0][0];        // 1200 floats
        float* sBias = (float*)&sB[0][4800];     // 225 floats
        int*   sOff  = (int*)&sB[0][5700];       // 225 ints: ty*80+tx = t + 65*(t/15)
        float* red   = (float*)&sB[1][0];        // 64 px x 4 g x 3 floats
        for (int i = t; i < 1200; i += 256) {
            int r = i / 80, xx = i - r * 80;
            int gy = y + r - 7;
            gy = gy < 0 ? -gy : (gy > 255 ? 510 - gy : gy);
            int gx = x0 + xx - 7;
            gx = gx < 0 ? -gx : (gx > 255 ? 510 - gx : gx);
            sRaw[i] = rawc[gy * 256 + gx];
        }
        if (t < 225) {
            sBias[t] = bias[t];
            sOff[t]  = t + 65 * (t / 15);
        }
        __syncthreads();

        float pm[2], ps[2], pa[2];
#pragma unroll
        for (int n = 0; n < 2; ++n) {
            float m = -1e30f, s = 0.f, a = 0.f;
            const int xb = col + n * 32;         // local x (gx_local = xb + tx)
#pragma unroll
            for (int ct = 0; ct < CT; ++ct) {
                const f32x16 A = acc[ct][n];
#pragma unroll
                for (int rh = 0; rh < 2; ++rh) {
                    int cb = (ctg0 + ct) * 2 + rh;
#pragma unroll
                    for (int j = 0; j < 8; ++j) {
                        int co = cb * 16 + (j & 3) + 8 * (j >> 2) + 4 * kh;
                        if (co < 225) {
                            float lv = A[rh * 8 + j] + sBias[co];
                            float pv = sRaw[sOff[co] + xb];
                            if (lv > m + 4.f) { float rs = __expf(m - lv); s *= rs; a *= rs; m = lv; }
                            float e = __expf(lv - m);
                            s += e; a += e * pv;
                        }
                    }
                }
            }
            // in-wave kh merge (lanes l <-> l^32 hold same px, other kh half)
            float mo = __shfl_xor(m, 32), so = __shfl_xor(s, 32), ao = __shfl_xor(a, 32);
            float M = fmaxf(m, mo);
            float e0 = __expf(m - M), e1 = __expf(mo - M);
            pm[n] = M;
            ps[n] = s * e0 + so * e1;
            pa[n] = a * e0 + ao * e1;
        }
        // cross-wave merge: 4 groups (wv), px = col + n*32
        if (kh == 0) {
#pragma unroll
            for (int n = 0; n < 2; ++n) {
                int px = col + n * 32;
                red[(px * 4 + wv) * 3 + 0] = pm[n];
                red[(px * 4 + wv) * 3 + 1] = ps[n];
                red[(px * 4 + wv) * 3 + 2] = pa[n];
            }
        }
        __syncthreads();
        if (t < 64) {
            float m = red[(t * 4) * 3], s = red[(t * 4) * 3 + 1], a = red[(t * 4) * 3 + 2];
#pragma unroll
            for (int gg = 1; gg < 4; ++gg) {
                float mg = red[(t * 4 + gg) * 3], sg = red[(t * 4 + gg) * 3 + 1], ag = red[(t * 4 + gg) * 3 + 2];
                float M = fmaxf(m, mg);
                float s0 = __expf(m - M), s1 = __expf(mg - M);
                s = s * s0 + sg * s1;
                a = a * s0 + ag * s1;
                m = M;
            }
            corr[y * 256 + x0 + t] = a / s;
        }
    } else {
        // epilogue: C/D col = l&31 (px), row = (reg&3)+8*(reg>>2)+4*kh
#pragma unroll
        for (int ct = 0; ct < CT; ++ct) {
            const int ctg = ctg0 + ct;
#pragma unroll
            for (int n = 0; n < 2; ++n) {
                const int xx = x0 + col + n * 32;
                const f32x16 A = acc[ct][n];
#pragma unroll
                for (int rh = 0; rh < 2; ++rh) {
                    int cb = ctg * 2 + rh;
                    if (cb >= CBmax) continue;
                    unsigned wd[4];
#pragma unroll
                    for (int jp = 0; jp < 4; ++jp) {
                        float vv[2];
#pragma unroll
                        for (int e = 0; e < 2; ++e) {
                            int j = jp * 2 + e;
                            int co = cb * 16 + (j & 3) + 8 * (j >> 2) + 4 * kh;
                            float bv = (co < Cout) ? bias[co] : 0.f;
                            float v = A[rh * 8 + j] + bv;
                            if (RELU) v = fmaxf(v, 0.f);
                            vv[e] = v;
                        }
                        wd[jp] = packbf2(vv[0], vv[1]);
                    }
                    *(uint4*)(ob + ((((size_t)cb << 8) + y) * 256 + xx) * 16 + (kh << 3)) =
                        make_uint4(wd[0], wd[1], wd[2], wd[3]);
                }
            }
        }
    }
}

// ---------------------------------------------------------------------------
// conv_v4 (reg-staged, generic W/RS) — kept for the freq-domain convs.
// ---------------------------------------------------------------------------
template<bool RELU, bool OUT_BF16, int CT>
__global__ __launch_bounds__(256, 3) void conv_v4(
    const unsigned short* __restrict__ inb, const short* __restrict__ wp,
    const float* __restrict__ bias, void* __restrict__ outv,
    int C32, int Cout, int COT, int W, int RSg, int CBmax)
{
    const int tilesx = (W + 127) >> 7;
    const int y  = blockIdx.x / tilesx;
    const int x0 = (blockIdx.x % tilesx) << 7;
    const int t  = threadIdx.x;
    const int l  = t & 63;
    const int col = l & 31, kh = l >> 5;
    const int wv = t >> 6;
    const int wct = wv & 1, wpt = wv >> 1;
    const int ctg0 = (blockIdx.y * 2 + wct) * CT;

    __shared__ __align__(16) unsigned char sB[26112];

    f32x16 acc[CT][2];
#pragma unroll
    for (int ct = 0; ct < CT; ++ct)
#pragma unroll
        for (int n = 0; n < 2; ++n)
#pragma unroll
            for (int i = 0; i < 16; ++i) acc[ct][n][i] = 0.f;

    int ba3[3];
#pragma unroll
    for (int dx = 0; dx < 3; ++dx) {
        int px = wpt * 64 + col + 3 + dx;
        ba3[dx] = px * 64 + ((kh ^ ((px >> 1) & 3)) << 4);
    }

    const int pxm = (t & 127) + 4, thalf = t >> 7;
    const int gxm = x0 + (t & 127);
    const bool gxok = gxm < W;
    const int offm_e = pxm * 64 + ((thalf ^ ((pxm >> 1) & 3)) << 4);
    const int hr = t >> 5, hj = t & 31, hg = hj >> 3, hp = hj & 7;
    const int hslot = hp + ((hp >> 2) << 7);
    const int hgx = x0 - 4 + hslot;
    const int hoff = hr * 8704 + hslot * 64 + ((hg ^ ((hslot >> 1) & 3)) << 4);
    const int hgy = y + hr - 1;
    const bool hok = (t < 96) && ((unsigned)hgy < 256u) && ((unsigned)hgx < (unsigned)W);

    auto STAGE = [&](int c32) {
        const int cb0 = c32 << 1;
#pragma unroll
        for (int k = 0; k < 6; ++k) {
            const int r = k >> 1;
            const int cb = cb0 + (k & 1);
            const int gy = y + r - 1;
            uint4 v = make_uint4(0, 0, 0, 0);
            if (gxok && (unsigned)gy < 256u)
                v = *(const uint4*)(inb + ((((size_t)cb << 8) + gy) * RSg + gxm) * 16 + (thalf << 3));
            *(uint4*)(sB + r * 8704 + (offm_e ^ ((k & 1) << 5))) = v;
        }
        if (t < 96) {
            uint4 v = make_uint4(0, 0, 0, 0);
            if (hok) v = *(const uint4*)(inb + ((((size_t)(cb0 + (hg >> 1)) << 8) + hgy) * RSg + hgx) * 16 + ((hg & 1) << 3));
            *(uint4*)(sB + hoff) = v;
        }
    };

    const bfrag* wA = (const bfrag*)wp;
    const int tstr = C32 * 2 * COT * 64;

    STAGE(0);
    __syncthreads();
    for (int c32 = 0; c32 < C32; ++c32) {
#pragma unroll 1
        for (int cs = 0; cs < 2; ++cs) {
            const int abase = ((c32 * 2 + cs) * COT + ctg0) * 64 + l;
            const int csx = cs << 5;
#pragma unroll
            for (int dy = 0; dy < 3; ++dy) {
                bfrag af[3][CT];
#pragma unroll
                for (int dx = 0; dx < 3; ++dx)
#pragma unroll
                    for (int ct = 0; ct < CT; ++ct)
                        af[dx][ct] = wA[abase + ct * 64 + (size_t)(dy * 3 + dx) * tstr];
                const unsigned char* rp = sB + dy * 8704;
#pragma unroll
                for (int dx = 0; dx < 3; ++dx) {
                    const int ba = ba3[dx] ^ csx;
                    bfrag b0 = *(const bfrag*)(rp + ba);
                    bfrag b1 = *(const bfrag*)(rp + ba + 2048);
#pragma unroll
                    for (int ct = 0; ct < CT; ++ct) {
                        acc[ct][0] = __builtin_amdgcn_mfma_f32_32x32x16_bf16(af[dx][ct], b0, acc[ct][0], 0, 0, 0);
                        acc[ct][1] = __builtin_amdgcn_mfma_f32_32x32x16_bf16(af[dx][ct], b1, acc[ct][1], 0, 0, 0);
                    }
                }
            }
        }
        __syncthreads();
        if (c32 + 1 < C32) { STAGE(c32 + 1); __syncthreads(); }
    }

    const int xBase = x0 + wpt * 64 + col;
#pragma unroll
    for (int ct = 0; ct < CT; ++ct) {
        const int ctg = ctg0 + ct;
#pragma unroll
        for (int n = 0; n < 2; ++n) {
            int xx = xBase + n * 32;
            if (xx >= W) continue;
            const f32x16 A = acc[ct][n];
            if (OUT_BF16) {
                unsigned short* ob = (unsigned short*)outv;
#pragma unroll
                for (int rh = 0; rh < 2; ++rh) {
                    int cb = ctg * 2 + rh;
                    if (cb >= CBmax) continue;
                    unsigned wd[4];
#pragma unroll
                    for (int jp = 0; jp < 4; ++jp) {
                        float vv[2];
#pragma unroll
                        for (int e = 0; e < 2; ++e) {
                            int j = jp * 2 + e;
                            int co = cb * 16 + (j & 3) + 8 * (j >> 2) + 4 * kh;
                            float bv = (co < Cout) ? bias[co] : 0.f;
                            float v = A[rh * 8 + j] + bv;
                            if (RELU) v = fmaxf(v, 0.f);
                            vv[e] = v;
                        }
                        wd[jp] = packbf2(vv[0], vv[1]);
                    }
                    *(uint4*)(ob + ((((size_t)cb << 8) + y) * RSg + xx) * 16 + (kh << 3)) =
                        make_uint4(wd[0], wd[1], wd[2], wd[3]);
                }
            } else {
                float* of = (float*)outv;
#pragma unroll
                for (int reg = 0; reg < 16; ++reg) {
                    int co = ctg * 32 + (reg & 3) + 8 * (reg >> 2) + 4 * kh;
                    if (co < Cout) {
                        float v = A[reg] + bias[co];
                        if (RELU) v = fmaxf(v, 0.f);
                        of[(((size_t)co << 8) + y) * RSg + xx] = v;
                    }
                }
            }
        }
    }
}

// ---------------------------------------------------------------------------
// Merged weight repack: 9 repack_wA jobs in ONE launch.
// ---------------------------------------------------------------------------
struct RepackJob { const float* w; unsigned short* o; int Cin, C32, Cout, COT, blk0, nblk; };
struct RepackJobs { RepackJob j[9]; };

__global__ __launch_bounds__(256) void repack_multi(RepackJobs J)
{
    int b = blockIdx.x;
    int ji = 0;
#pragma unroll
    for (int k = 1; k < 9; ++k) if (b >= J.j[k].blk0) ji = k;
    const RepackJob jb = J.j[ji];
    int rb = b - jb.blk0;
    int total = 9 * jb.C32 * 2 * jb.COT * 512;
    for (int i = rb * 256 + threadIdx.x; i < total; i += jb.nblk * 256) {
        int j = i & 7;
        int l = (i >> 3) & 63;
        int rest = i >> 9;
        int ct = rest % jb.COT; rest /= jb.COT;
        int cs = rest & 1; rest >>= 1;
        int c32 = rest % jb.C32;
        int tap = rest / jb.C32;
        int co = ct * 32 + (l & 31);
        int s = ((l >> 5) << 3) + j;
        int ci = c32 * 32 + cs * 16 + PERM4(s);
        float v = (co < jb.Cout && ci < jb.Cin) ? jb.w[((size_t)co * jb.Cin + ci) * 9 + tap] : 0.f;
        jb.o[i] = (unsigned short)bf16rne(v);
    }
}

// fp32 NCHW [C][256][256] -> bf16 blocked [CB][y][x][16] with PERM slots
__global__ __launch_bounds__(256) void cvt_blocked(
    const float* __restrict__ src, unsigned short* __restrict__ dst, int C)
{
    int cb = blockIdx.x >> 8;
    int y  = blockIdx.x & 255;
    int x  = threadIdx.x;
    unsigned wd[8];
#pragma unroll
    for (int q = 0; q < 8; ++q) {
        float v[2];
#pragma unroll
        for (int e = 0; e < 2; ++e) {
            int s = q * 2 + e;
            int ci = (cb << 4) + PERM4(s);
            v[e] = (ci < C) ? src[((size_t)ci * 256 + y) * 256 + x] : 0.f;
        }
        wd[q] = packbf2(v[0], v[1]);
    }
    unsigned short* dp = dst + (((size_t)cb << 16) + (y << 8) + x) * 16;
    *(uint4*)dp = make_uint4(wd[0], wd[1], wd[2], wd[3]);
    *(uint4*)(dp + 8) = make_uint4(wd[4], wd[5], wd[6], wd[7]);
}

// ---------------------------------------------------------------------------
// Refinement
// ---------------------------------------------------------------------------
__global__ __launch_bounds__(256) void repack_wr2(
    const float* __restrict__ cw2, unsigned short* __restrict__ o)
{
    int i = blockIdx.x * 256 + threadIdx.x;
    if (i >= 10240) return;
    int k = i & 31, rest = i >> 5;
    int co = rest & 15;
    int kt = (rest >> 4) % 5;
    int ch = rest / 80;
    int tap = 2 * kt + (k >= 16 ? 1 : 0), ci = k & 15;
    float v = 0.f;
    if (tap < 9) v = cw2[(((size_t)ch * 16 + co) * 16 + ci) * 9 + tap];
    o[i] = (unsigned short)bf16rne(v);
}

__global__ __launch_bounds__(256) void refine1_kernel(
    const float* __restrict__ corrected, const float* __restrict__ cw1,
    const float* __restrict__ cb1, unsigned short* __restrict__ h1b)
{
    const int c = blockIdx.x >> 8;
    const int y = blockIdx.x & 255;
    const int t = threadIdx.x;
    __shared__ float sIn[3][258];
    __shared__ float sW[144];
    __shared__ float sBv[16];
    if (t < 144) sW[t] = cw1[c * 144 + t];
    if (t >= 144 && t < 160) sBv[t - 144] = cb1[c * 16 + (t - 144)];
    for (int i = t; i < 774; i += 256) {
        int r = i / 258, xx = i % 258;
        int gy = y + r - 1, gx = xx - 1;
        sIn[r][xx] = ((unsigned)gy < 256u && (unsigned)gx < 256u)
                   ? corrected[((size_t)c * 256 + gy) * 256 + gx] : 0.f;
    }
    __syncthreads();
    float a[9];
#pragma unroll
    for (int dy = 0; dy < 3; ++dy)
#pragma unroll
        for (int dx = 0; dx < 3; ++dx) a[dy * 3 + dx] = sIn[dy][t + dx];
    unsigned short ov[16];
#pragma unroll
    for (int co = 0; co < 16; ++co) {
        float acc = sBv[co];
#pragma unroll
        for (int tap = 0; tap < 9; ++tap) acc += a[tap] * sW[co * 9 + tap];
        acc = fmaxf(acc, 0.f);
        ov[co] = (unsigned short)bf16rne(acc);
    }
    unsigned short* op = h1b + ((((size_t)c * 256 + y) * 256 + t) << 4);
    *(uint4*)op = *(uint4*)ov;
    *(uint4*)(op + 8) = *(uint4*)(ov + 8);
}

__global__ __launch_bounds__(256) void refine2_mfma(
    const unsigned short* __restrict__ h1b, const unsigned short* __restrict__ wr2,
    const float* __restrict__ cb2, unsigned short* __restrict__ h2b)
{
    const int c = blockIdx.x >> 8;
    const int y = blockIdx.x & 255;
    const int t = threadIdx.x;
    const int l15 = t & 15, lg = (t >> 4) & 3, wv = t >> 6;

    __shared__ __align__(16) unsigned char sA[3 * 258 * 32];

    for (int i = t; i < 1548; i += 256) {
        int r = i / 516, u = i % 516;
        int px = u >> 1, half = u & 1;
        int gy = y + r - 1, gx = px - 1;
        uint4 v = make_uint4(0, 0, 0, 0);
        if ((unsigned)gy < 256u && (unsigned)gx < 256u)
            v = *(const uint4*)(h1b + ((((size_t)c * 256 + gy) * 256 + gx) << 4) + (half << 3));
        *(uint4*)(sA + r * 8256 + px * 32 + ((half ^ ((px >> 2) & 1)) << 4)) = v;
    }
    __syncthreads();

    f32x4 acc[4];
#pragma unroll
    for (int n = 0; n < 4; ++n) acc[n] = (f32x4){0.f, 0.f, 0.f, 0.f};
    const bfrag* wf = (const bfrag*)(wr2 + (size_t)c * 2560);
    const int strip = wv * 64;
#pragma unroll
    for (int kt = 0; kt < 5; ++kt) {
        bfrag a = wf[(kt * 16 + l15) * 4 + lg];
        int tap1 = 2 * kt + 1; if (tap1 > 8) tap1 = 8;
        int tap = (lg < 2) ? (2 * kt) : tap1;
        int dy = tap / 3, dx = tap % 3;
#pragma unroll
        for (int n = 0; n < 4; ++n) {
            int pxs = strip + n * 16 + l15 + dx;
            bfrag b = *(const bfrag*)(sA + dy * 8256 + pxs * 32 +
                                      (((lg & 1) ^ ((pxs >> 2) & 1)) << 4));
            acc[n] = __builtin_amdgcn_mfma_f32_16x16x32_bf16(a, b, acc[n], 0, 0, 0);
        }
    }

#pragma unroll
    for (int n = 0; n < 4; ++n) {
        int px = strip + n * 16 + l15;
        unsigned short ov[4];
#pragma unroll
        for (int r = 0; r < 4; ++r) {
            int co = lg * 4 + r;
            float v = acc[n][r] + cb2[c * 16 + co];
            v = fmaxf(v, 0.f);
            ov[r] = (unsigned short)bf16rne(v);
        }
        *(ushort4*)(h2b + ((((size_t)c * 256 + y) * 256 + px) << 4) + lg * 4) = *(ushort4*)ov;
    }
}

__global__ __launch_bounds__(256) void refine3_kernel(
    const unsigned short* __restrict__ h2b, const float* __restrict__ cw3,
    const float* __restrict__ cb3, const float* __restrict__ raw,
    float* __restrict__ out)
{
    const int c = blockIdx.x >> 8;
    const int y = blockIdx.x & 255;
    const int t = threadIdx.x;
    __shared__ __align__(16) unsigned char sA[3 * 258 * 32];
    __shared__ float sW[144];
    if (t < 144) sW[t] = cw3[c * 144 + t];
    for (int i = t; i < 1548; i += 256) {
        int r = i / 516, u = i % 516;
        int px = u >> 1, half = u & 1;
        int gy = y + r - 1, gx = px - 1;
        uint4 v = make_uint4(0, 0, 0, 0);
        if ((unsigned)gy < 256u && (unsigned)gx < 256u)
            v = *(const uint4*)(h2b + ((((size_t)c * 256 + gy) * 256 + gx) << 4) + (half << 3));
        *(uint4*)(sA + r * 8256 + px * 32 + ((half ^ ((px >> 2) & 1)) << 4)) = v;
    }
    __syncthreads();
    float acc = cb3[c];
#pragma unroll
    for (int tap = 0; tap < 9; ++tap) {
        int dy = tap / 3, dx = tap % 3;
        int px = t + dx;
        const unsigned char* p = sA + dy * 8256 + px * 32;
        int sw = ((px >> 2) & 1) << 4;
        us8 h0 = *(const us8*)(p + (sw ^ 0));
        us8 h1 = *(const us8*)(p + (sw ^ 16));
#pragma unroll
        for (int j = 0; j < 8; ++j) acc += bf2f(h0[j]) * sW[j * 9 + tap];
#pragma unroll
        for (int j = 0; j < 8; ++j) acc += bf2f(h1[j]) * sW[(8 + j) * 9 + tap];
    }
    size_t idx = ((size_t)c * 256 + y) * 256 + t;
    float v = raw[idx] + acc;
    out[idx] = fminf(fmaxf(v, 0.f), 1.f);
}

// ---------------------------------------------------------------------------
// DFT kernels — 4 independent accumulators break the serial fp add chain.
// ---------------------------------------------------------------------------
__global__ __launch_bounds__(256) void rdft_row_kernel(
    const float* __restrict__ x, float2* __restrict__ z)
{
    int cy = blockIdx.x;
    __shared__ float row[256];
    __shared__ float ct[256], st[256];
    int t = threadIdx.x;
    row[t] = x[cy * 256 + t];
    float a = (2.0f * PI_F / 256.0f) * (float)t;
    ct[t] = cosf(a);
    st[t] = sinf(a);
    __syncthreads();
    if (t < 129) {
        float re0 = 0.f, re1 = 0.f, re2 = 0.f, re3 = 0.f;
        float im0 = 0.f, im1 = 0.f, im2 = 0.f, im3 = 0.f;
        const int t2 = (2 * t) & 255, t3 = (3 * t) & 255, t4 = (4 * t) & 255;
        int i0 = 0;
        for (int n = 0; n < 256; n += 4) {
            int i1 = (i0 + t) & 255, i2 = (i0 + t2) & 255, i3 = (i0 + t3) & 255;
            float v0 = row[n], v1 = row[n + 1], v2 = row[n + 2], v3 = row[n + 3];
            re0 += v0 * ct[i0]; im0 -= v0 * st[i0];
            re1 += v1 * ct[i1]; im1 -= v1 * st[i1];
            re2 += v2 * ct[i2]; im2 -= v2 * st[i2];
            re3 += v3 * ct[i3]; im3 -= v3 * st[i3];
            i0 = (i0 + t4) & 255;
        }
        z[cy * 129 + t] = make_float2((re0 + re1) + (re2 + re3),
                                      (im0 + im1) + (im2 + im3));
    }
}

__global__ __launch_bounds__(256) void dft_col_fwd2(
    const float2* __restrict__ z, unsigned short* __restrict__ fri16)
{
    int c  = blockIdx.x >> 8;
    int k1 = blockIdx.x & 255;
    __shared__ float ct[256], st[256];
    int t = threadIdx.x;
    float a = (2.0f * PI_F / 256.0f) * (float)t;
    ct[t] = cosf(a);
    st[t] = sinf(a);
    __syncthreads();
    if (t < 129) {
        float re0 = 0.f, re1 = 0.f, re2 = 0.f, re3 = 0.f;
        float im0 = 0.f, im1 = 0.f, im2 = 0.f, im3 = 0.f;
        const int k2 = (2 * k1) & 255, k3 = (3 * k1) & 255, k4 = (4 * k1) & 255;
        int i0 = 0;
        const float2* zp = z + (size_t)c * 256 * 129 + t;
        for (int n1 = 0; n1 < 256; n1 += 4) {
            int i1 = (i0 + k1) & 255, i2 = (i0 + k2) & 255, i3 = (i0 + k3) & 255;
            float2 z0 = zp[(size_t)n1 * 129];
            float2 z1 = zp[(size_t)(n1 + 1) * 129];
            float2 z2 = zp[(size_t)(n1 + 2) * 129];
            float2 z3 = zp[(size_t)(n1 + 3) * 129];
            re0 += z0.x * ct[i0] + z0.y * st[i0];  im0 += z0.y * ct[i0] - z0.x * st[i0];
            re1 += z1.x * ct[i1] + z1.y * st[i1];  im1 += z1.y * ct[i1] - z1.x * st[i1];
            re2 += z2.x * ct[i2] + z2.y * st[i2];  im2 += z2.y * ct[i2] - z2.x * st[i2];
            re3 += z3.x * ct[i3] + z3.y * st[i3];  im3 += z3.y * ct[i3] - z3.x * st[i3];
            i0 = (i0 + k4) & 255;
        }
        const float sc = 1.0f / 256.0f;
        size_t base = ((size_t)k1 * 132 + t) * 16;
        fri16[base + c]     = (unsigned short)bf16rne(((re0 + re1) + (re2 + re3)) * sc);
        fri16[base + 8 + c] = (unsigned short)bf16rne(((im0 + im1) + (im2 + im3)) * sc);
    }
}

// fused inverse: column inverse DFT (k1 -> n1) into LDS, then Hermitian row
// inverse (k2 -> n2) and accumulate into corrected. One block per (c, n1).
__global__ __launch_bounds__(256) void idft_fused_kernel(
    const float* __restrict__ g, float* __restrict__ corrected)
{
    int c  = blockIdx.x >> 8;
    int n1 = blockIdx.x & 255;
    __shared__ float2 yrow[129];
    __shared__ float ct[256], st[256];
    int t = threadIdx.x;
    float a = (2.0f * PI_F / 256.0f) * (float)t;
    ct[t] = cosf(a);
    st[t] = sinf(a);
    __syncthreads();
    if (t < 129) {
        float re0 = 0.f, re1 = 0.f, re2 = 0.f, re3 = 0.f;
        float im0 = 0.f, im1 = 0.f, im2 = 0.f, im3 = 0.f;
        const int n2_ = (2 * n1) & 255, n3_ = (3 * n1) & 255, n4_ = (4 * n1) & 255;
        int i0 = 0;
        const float* gr0 = g + (size_t)c * 256 * 132 + t;
        const float* gi0 = g + (size_t)(4 + c) * 256 * 132 + t;
        for (int k1 = 0; k1 < 256; k1 += 4) {
            int i1 = (i0 + n1) & 255, i2 = (i0 + n2_) & 255, i3 = (i0 + n3_) & 255;
            float gr_0 = gr0[(size_t)k1 * 132],       gi_0 = gi0[(size_t)k1 * 132];
            float gr_1 = gr0[(size_t)(k1 + 1) * 132], gi_1 = gi0[(size_t)(k1 + 1) * 132];
            float gr_2 = gr0[(size_t)(k1 + 2) * 132], gi_2 = gi0[(size_t)(k1 + 2) * 132];
            float gr_3 = gr0[(size_t)(k1 + 3) * 132], gi_3 = gi0[(size_t)(k1 + 3) * 132];
            re0 += gr_0 * ct[i0] - gi_0 * st[i0];  im0 += gi_0 * ct[i0] + gr_0 * st[i0];
            re1 += gr_1 * ct[i1] - gi_1 * st[i1];  im1 += gi_1 * ct[i1] + gr_1 * st[i1];
            re2 += gr_2 * ct[i2] - gi_2 * st[i2];  im2 += gi_2 * ct[i2] + gr_2 * st[i2];
            re3 += gr_3 * ct[i3] - gi_3 * st[i3];  im3 += gi_3 * ct[i3] + gr_3 * st[i3];
            i0 = (i0 + n4_) & 255;
        }
        yrow[t] = make_float2((re0 + re1) + (re2 + re3), (im0 + im1) + (im2 + im3));
    }
    __syncthreads();
    float acc0 = yrow[0].x + ((t & 1) ? -yrow[128].x : yrow[128].x);
    float a1 = 0.f, a2 = 0.f, a3 = 0.f, a4 = 0.f;
    const int t2 = (2 * t) & 255, t3 = (3 * t) & 255, t4 = (4 * t) & 255;
    int i1 = t;            // idx for k=1
    int k = 1;
    for (; k + 3 <= 127; k += 4) {
        int j0 = i1, j1 = (i1 + t) & 255, j2 = (i1 + t2) & 255, j3 = (i1 + t3) & 255;
        float2 y0 = yrow[k], y1 = yrow[k + 1], y2 = yrow[k + 2], y3 = yrow[k + 3];
        a1 += y0.x * ct[j0] - y0.y * st[j0];
        a2 += y1.x * ct[j1] - y1.y * st[j1];
        a3 += y2.x * ct[j2] - y2.y * st[j2];
        a4 += y3.x * ct[j3] - y3.y * st[j3];
        i1 = (i1 + t4) & 255;
    }
    for (; k <= 127; ++k) {
        float2 yv = yrow[k];
        a1 += yv.x * ct[i1] - yv.y * st[i1];
        i1 = (i1 + t) & 255;
    }
    float acc = acc0 + 2.0f * ((a1 + a2) + (a3 + a4));
    corrected[c * 65536 + n1 * 256 + t] += acc * (1.0f / 256.0f);
}

// ---------------------------------------------------------------------------
extern "C" void kernel_launch(void* const* d_in, const int* in_sizes, int n_in,
                              void* d_out, int out_size, void* d_ws, size_t ws_size,
                              hipStream_t stream)
{
    const float* raw = (const float*)d_in[0];
    const float* ab  = (const float*)d_in[1];
    const float* pw1 = (const float*)d_in[2];  const float* pb1 = (const float*)d_in[3];
    const float* pw2 = (const float*)d_in[4];  const float* pb2 = (const float*)d_in[5];
    const float* pw3 = (const float*)d_in[6];  const float* pb3 = (const float*)d_in[7];
    const float* fw1 = (const float*)d_in[8];  const float* fb1 = (const float*)d_in[9];
    const float* fw2 = (const float*)d_in[10]; const float* fb2 = (const float*)d_in[11];
    const float* fw3 = (const float*)d_in[12]; const float* fb3 = (const float*)d_in[13];
    const float* cw1 = (const float*)d_in[14]; const float* cb1 = (const float*)d_in[15];
    const float* cw2 = (const float*)d_in[16]; const float* cb2 = (const float*)d_in[17];
    const float* cw3 = (const float*)d_in[18]; const float* cb3 = (const float*)d_in[19];
    float* out = (float*)d_out;

    char* B = (char*)d_ws;
    unsigned short* h1b     = (unsigned short*)(B);              // 33,554,432 B (16 cb)
    unsigned short* h2b     = (unsigned short*)(B + 33554432);   // 16,777,216 B (8 cb)
    unsigned short* h1r     = (unsigned short*)(B + 33554432);   // alias (after psf)
    unsigned short* h2r     = (unsigned short*)(B + 41943040);
    float* corrected = (float*)(B + 50331648);                   // 1,048,576 B
    float2* zbuf     = (float2*)(B + 51380224);                  // 2,113,536 B
    unsigned short* fri16 = (unsigned short*)(B + 53493760);     // 2,162,688 B (2 cb, RS 132)
    unsigned short* g1b   = (unsigned short*)(B + 55656448);     // 4,325,376 B (4 cb)
    unsigned short* g2b   = (unsigned short*)(B + 59981824);     // 4,325,376 B
    float* gf        = (float*)(B + 64307200);                   // 1,081,344 B
    unsigned short* rw1  = (unsigned short*)(B + 65388544);      // 589,824 B
    unsigned short* rw2  = (unsigned short*)(B + 65978368);      // 589,824 B
    unsigned short* rw3  = (unsigned short*)(B + 66568192);      // 4 x 589,824 B
    unsigned short* rwf1 = (unsigned short*)(B + 68927488);      // 36,864 B
    unsigned short* rwf2 = (unsigned short*)(B + 68964352);      // 73,728 B
    unsigned short* rwf3 = (unsigned short*)(B + 69038080);      // 73,728 B
    unsigned short* wr2r = (unsigned short*)(B + 69111808);      // 20,480 B
    unsigned short* ab16 = (unsigned short*)(B + 69132288);      // 16,777,216 B

    dim3 blk(256);

    // merged weight repacks (one launch) + remaining converts
    RepackJobs J;
    J.j[0] = { pw1,                    rw1,                128, 4, 256, 8,    0, 512 };
    J.j[1] = { pw2,                    rw2,                256, 8, 128, 4,  512, 512 };
    J.j[2] = { pw3 + 0 * 259200,       rw3 + 0 * 294912,   128, 4, 225, 8, 1024, 512 };
    J.j[3] = { pw3 + 1 * 259200,       rw3 + 1 * 294912,   128, 4, 225, 8, 1536, 512 };
    J.j[4] = { pw3 + 2 * 259200,       rw3 + 2 * 294912,   128, 4, 225, 8, 2048, 512 };
    J.j[5] = { pw3 + 3 * 259200,       rw3 + 3 * 294912,   128, 4, 225, 8, 2560, 512 };
    J.j[6] = { fw1,                    rwf1,                 8, 1,  64, 2, 3072,  64 };
    J.j[7] = { fw2,                    rwf2,                64, 2,  64, 2, 3136, 128 };
    J.j[8] = { fw3,                    rwf3,                64, 2,   8, 2, 3264, 128 };
    repack_multi<<<3392, blk, 0, stream>>>(J);
    repack_wr2<<<40, blk, 0, stream>>>(cw2, wr2r);
    cvt_blocked<<<2048, blk, 0, stream>>>(ab, ab16, 128);

    // conv1: ab16(128) -> h1b(256), relu   [block = 256co x 64px, CT=2]
    conv_v9<true, 2, false><<<1024, blk, 0, stream>>>(
        ab16, (const short*)rw1, pb1, h1b, 4, 256, 8, 16, nullptr, nullptr);
    // conv2: h1b(256) -> h2b(128), relu    [block = 128co x 64px, CT=1]
    conv_v9<true, 1, false><<<1024, blk, 0, stream>>>(
        h1b, (const short*)rw2, pb2, h2b, 8, 128, 4, 8, nullptr, nullptr);
    // psf conv with FUSED softmax+patch epilogue, all 4 channels in ONE launch
    conv_v9<false, 2, true><<<dim3(1024, 4), blk, 0, stream>>>(
        h2b, (const short*)rw3, pb3, h1b, 4, 225, 8, 15, raw, corrected);
    // forward rfft2 (ortho)
    rdft_row_kernel<<<1024, blk, 0, stream>>>(corrected, zbuf);
    hipMemsetAsync(fri16, 0, 2162688, stream);
    dft_col_fwd2<<<1024, blk, 0, stream>>>(zbuf, fri16);
    // freq-domain convs (W=129, RS=132)
    conv_v4<true, true, 1><<<dim3(512, 1), blk, 0, stream>>>(
        fri16, (const short*)rwf1, fb1, g1b, 1, 64, 2, 129, 132, 4);
    conv_v4<true, true, 1><<<dim3(512, 1), blk, 0, stream>>>(
        g1b, (const short*)rwf2, fb2, g2b, 2, 64, 2, 129, 132, 4);
    conv_v4<false, false, 1><<<dim3(512, 1), blk, 0, stream>>>(
        g2b, (const short*)rwf3, fb3, gf, 2, 8, 2, 129, 132, 0);
    // fused inverse irfft2 (ortho), accumulate into corrected
    idft_fused_kernel<<<1024, blk, 0, stream>>>(gf, corrected);
    // per-channel refinement, fused final clip
    refine1_kernel<<<1024, blk, 0, stream>>>(corrected, cw1, cb1, h1r);
    refine2_mfma<<<1024, blk, 0, stream>>>(h1r, wr2r, cb2, h2r);
    refine3_kernel<<<1024, blk, 0, stream>>>(h2r, cw3, cb3, raw, out);
}